// Round 2
// baseline (1321.646 us; speedup 1.0000x reference)
//
#include <hip/hip_runtime.h>
#include <hip/hip_bf16.h>
#include <math.h>

#define L_TOK 1569
#define DM 192
#define DI 384
#define DS 16
#define DTR 12
#define DCONV 4
#define XDBL_N (DTR + 2*DS)   // 44
#define DEPTH 8
#define NCHUNK 25
#define CLEN 64
#define NPATCH 1568

// ---------------------------------------------------------------------------
// im2col: px[patch][k] = x[c][t][h*16+p][w*16+q], k = c*256+p*16+q.
// Also writes token 0 (cls + pos).
// ---------------------------------------------------------------------------
__global__ __launch_bounds__(256) void im2col_kernel(
    const float* __restrict__ x, const float* __restrict__ cls,
    const float* __restrict__ pos, float* __restrict__ px,
    float* __restrict__ tok0) {
  if (blockIdx.x == 0 && threadIdx.x < DM)
    tok0[threadIdx.x] = cls[threadIdx.x] + pos[threadIdx.x];
  int gid = blockIdx.x * 256 + threadIdx.x;
  if (gid >= NPATCH * 192) return;      // 192 float4 per patch
  int patch = gid / 192;
  int r = gid % 192;
  int c = r / 64;
  int p = (r >> 2) & 15;
  int q = (r & 3) * 4;
  int t = patch / 196, hw = patch % 196, hh = hw / 14, w = hw % 14;
  const float* src = x + ((size_t)(c*8 + t)*224 + hh*16 + p)*224 + w*16 + q;
  *(float4*)(px + (size_t)patch*768 + r*4) = *(const float4*)src;
}

// ---------------------------------------------------------------------------
// LayerNorm over 192 features. One wave per token, 3 elems/lane.
// ---------------------------------------------------------------------------
__global__ __launch_bounds__(64) void ln_kernel(
    const float* __restrict__ in, float* __restrict__ out,
    const float* __restrict__ g, const float* __restrict__ b) {
  int tokn = blockIdx.x;
  int lane = threadIdx.x;
  const float* row = in + (size_t)tokn*DM;
  float x0 = row[lane], x1 = row[lane+64], x2 = row[lane+128];
  float s = x0 + x1 + x2;
  float s2 = x0*x0 + x1*x1 + x2*x2;
#pragma unroll
  for (int off = 1; off < 64; off <<= 1) {
    s  += __shfl_xor(s,  off, 64);
    s2 += __shfl_xor(s2, off, 64);
  }
  float m = s * (1.0f/192.0f);
  float v = s2 * (1.0f/192.0f) - m*m;
  float rs = rsqrtf(v + 1e-5f);
  float* orow = out + (size_t)tokn*DM;
  orow[lane]     = (x0 - m)*rs*g[lane]     + b[lane];
  orow[lane+64]  = (x1 - m)*rs*g[lane+64]  + b[lane+64];
  orow[lane+128] = (x2 - m)*rs*g[lane+128] + b[lane+128];
}

// ---------------------------------------------------------------------------
// Pipelined fp32 GEMM: C[M,N] = A[M,K] * B[N,K]^T, K % 16 == 0.
// Double-buffered LDS, loads for tile k+1 issued before compute of tile k,
// one barrier per k-step.
// epi: 0 = (+bias), 2 = C += v (residual), 3 = +bias +add[m*ldc+n]
// ---------------------------------------------------------------------------
__global__ __launch_bounds__(256) void gemm2_kernel(
    const float* __restrict__ A, int lda,
    const float* __restrict__ B, int ldb,
    float* __restrict__ C, int ldc,
    int M, int N, int K,
    const float* __restrict__ bias,
    const float* __restrict__ add, int epi) {
  __shared__ float As[2][16][68];
  __shared__ float Bs[2][16][68];
  int tid = threadIdx.x;
  int m0 = blockIdx.y * 64, n0 = blockIdx.x * 64;
  int lr = tid >> 2;          // 0..63
  int lk = (tid & 3) * 4;     // 0,4,8,12
  int trow = tid >> 4;        // 0..15
  int tcol = tid & 15;        // 0..15
  float acc[4][4] = {};

  const int mA = m0 + lr;
  const int nB = n0 + lr;
  const float* ap = (mA < M) ? (A + (size_t)mA*lda + lk) : nullptr;
  const float* bp = (nB < N) ? (B + (size_t)nB*ldb + lk) : nullptr;
  const float4 z4 = {0.f, 0.f, 0.f, 0.f};

  // prologue: tile 0
  {
    float4 av = ap ? *(const float4*)(ap + 0) : z4;
    float4 bv = bp ? *(const float4*)(bp + 0) : z4;
    As[0][lk+0][lr] = av.x; As[0][lk+1][lr] = av.y;
    As[0][lk+2][lr] = av.z; As[0][lk+3][lr] = av.w;
    Bs[0][lk+0][lr] = bv.x; Bs[0][lk+1][lr] = bv.y;
    Bs[0][lk+2][lr] = bv.z; Bs[0][lk+3][lr] = bv.w;
  }
  __syncthreads();

  int nt = K >> 4;
  for (int i = 0; i < nt; ++i) {
    int cur = i & 1, nxt = cur ^ 1;
    float4 av, bv;
    bool pf = (i + 1 < nt);
    if (pf) {
      int k0 = (i + 1) << 4;
      av = ap ? *(const float4*)(ap + k0) : z4;
      bv = bp ? *(const float4*)(bp + k0) : z4;
    }
#pragma unroll
    for (int kk = 0; kk < 16; ++kk) {
      float4 a = *(const float4*)&As[cur][kk][trow*4];
      float4 b = *(const float4*)&Bs[cur][kk][tcol*4];
      float avv[4] = {a.x, a.y, a.z, a.w};
      float bvv[4] = {b.x, b.y, b.z, b.w};
#pragma unroll
      for (int ii = 0; ii < 4; ++ii)
#pragma unroll
        for (int jj = 0; jj < 4; ++jj)
          acc[ii][jj] = fmaf(avv[ii], bvv[jj], acc[ii][jj]);
    }
    if (pf) {
      As[nxt][lk+0][lr] = av.x; As[nxt][lk+1][lr] = av.y;
      As[nxt][lk+2][lr] = av.z; As[nxt][lk+3][lr] = av.w;
      Bs[nxt][lk+0][lr] = bv.x; Bs[nxt][lk+1][lr] = bv.y;
      Bs[nxt][lk+2][lr] = bv.z; Bs[nxt][lk+3][lr] = bv.w;
      __syncthreads();
    }
  }

#pragma unroll
  for (int i = 0; i < 4; ++i) {
    int m = m0 + trow*4 + i;
    if (m >= M) continue;
#pragma unroll
    for (int j = 0; j < 4; ++j) {
      int n = n0 + tcol*4 + j;
      if (n >= N) continue;
      float v = acc[i][j];
      if (bias) v += bias[n];
      if (epi == 3) v += add[(size_t)m*ldc + n];
      float* cp = C + (size_t)m*ldc + n;
      if (epi == 2) v += *cp;
      *cp = v;
    }
  }
}

// ---------------------------------------------------------------------------
// xdbl GEMM with conv+SiLU fused into the A-staging:
// A[t][d] = silu(bc[d] + sum_j xz[t-3+j][d] * Wc[d][j]), implicit from xz.
// C[M=L_TOK, N=44] = A @ Wx^T.
// ---------------------------------------------------------------------------
__global__ __launch_bounds__(256) void gemm_conv_kernel(
    const float* __restrict__ xz,
    const float* __restrict__ Wc, const float* __restrict__ bc,
    const float* __restrict__ B, float* __restrict__ C) {
  __shared__ float As[2][16][68];
  __shared__ float Bs[2][16][68];
  __shared__ float wcs[DI*DCONV];
  __shared__ float bcs[DI];
  const int M = L_TOK, N = XDBL_N, K = DI;
  int tid = threadIdx.x;
  int m0 = blockIdx.y * 64, n0 = blockIdx.x * 64;
  int lr = tid >> 2;
  int lk = (tid & 3) * 4;
  int trow = tid >> 4;
  int tcol = tid & 15;
  float acc[4][4] = {};

  for (int i = tid; i < DI*DCONV; i += 256) wcs[i] = Wc[i];
  for (int i = tid; i < DI; i += 256) bcs[i] = bc[i];

  const int t = m0 + lr;
  const int nB = n0 + lr;
  const float* bp = (nB < N) ? (B + (size_t)nB*K + lk) : nullptr;
  const float4 z4 = {0.f, 0.f, 0.f, 0.f};

  // A tap loads for channel block (k0+lk .. +3), tokens t-3..t
  auto load_taps = [&](int k0, float rv[4][4]) {
#pragma unroll
    for (int j = 0; j < 4; ++j) {
      int ts = t - 3 + j;
      float4 v = z4;
      if (t < M && ts >= 0)
        v = *(const float4*)(xz + (size_t)ts*(2*DI) + k0 + lk);
      rv[j][0] = v.x; rv[j][1] = v.y; rv[j][2] = v.z; rv[j][3] = v.w;
    }
  };
  auto store_A = [&](int buf, int k0, float rv[4][4]) {
#pragma unroll
    for (int c = 0; c < 4; ++c) {
      int d = k0 + lk + c;
      float u = bcs[d];
#pragma unroll
      for (int j = 0; j < 4; ++j) u = fmaf(rv[j][c], wcs[d*4 + j], u);
      u = u / (1.0f + expf(-u));
      As[buf][lk+c][lr] = u;
    }
  };

  __syncthreads();   // wcs/bcs ready

  {
    float rv[4][4];
    load_taps(0, rv);
    float4 bv = bp ? *(const float4*)(bp + 0) : z4;
    store_A(0, 0, rv);
    Bs[0][lk+0][lr] = bv.x; Bs[0][lk+1][lr] = bv.y;
    Bs[0][lk+2][lr] = bv.z; Bs[0][lk+3][lr] = bv.w;
  }
  __syncthreads();

  int nt = K >> 4;
  for (int i = 0; i < nt; ++i) {
    int cur = i & 1, nxt = cur ^ 1;
    float rv[4][4];
    float4 bv;
    bool pf = (i + 1 < nt);
    int k0n = (i + 1) << 4;
    if (pf) {
      load_taps(k0n, rv);
      bv = bp ? *(const float4*)(bp + k0n) : z4;
    }
#pragma unroll
    for (int kk = 0; kk < 16; ++kk) {
      float4 a = *(const float4*)&As[cur][kk][trow*4];
      float4 b = *(const float4*)&Bs[cur][kk][tcol*4];
      float avv[4] = {a.x, a.y, a.z, a.w};
      float bvv[4] = {b.x, b.y, b.z, b.w};
#pragma unroll
      for (int ii = 0; ii < 4; ++ii)
#pragma unroll
        for (int jj = 0; jj < 4; ++jj)
          acc[ii][jj] = fmaf(avv[ii], bvv[jj], acc[ii][jj]);
    }
    if (pf) {
      store_A(nxt, k0n, rv);
      Bs[nxt][lk+0][lr] = bv.x; Bs[nxt][lk+1][lr] = bv.y;
      Bs[nxt][lk+2][lr] = bv.z; Bs[nxt][lk+3][lr] = bv.w;
      __syncthreads();
    }
  }

#pragma unroll
  for (int i = 0; i < 4; ++i) {
    int m = m0 + trow*4 + i;
    if (m >= M) continue;
#pragma unroll
    for (int j = 0; j < 4; ++j) {
      int n = n0 + tcol*4 + j;
      if (n >= N) continue;
      C[(size_t)m*XDBL_N + n] = acc[i][j];
    }
  }
}

// ---------------------------------------------------------------------------
// Selective scan. conv+SiLU and delta = softplus(xdbl[:, :12] @ W_dt^T + b_dt)
// are recomputed in-block from xz / xdbl (no uc/delta buffers).
// Phase 1: per-chunk local scan from zero state.
// grid.x = 24 d-groups (16 d each), grid.y = 25 chunks. 256 thr = 16d x 16n.
// ---------------------------------------------------------------------------
__device__ __forceinline__ void scan_stage_common(
    const float* __restrict__ xz, const float* __restrict__ xdbl,
    const float* __restrict__ Wc, const float* __restrict__ bc,
    const float* __restrict__ W_dt, const float* __restrict__ b_dt,
    int d0, int t0,
    float xs[CLEN+3][16], float us[CLEN][16], float ds[CLEN][16],
    float bs[CLEN][16], float xd12[CLEN][12],
    float wdt[16][12], float wcs[16][4], float bds[16], float bcs[16],
    float cs[CLEN][16], float zs[CLEN][16], bool p3) {
  int tid = threadIdx.x;
  for (int i = tid; i < (CLEN+3)*16; i += 256) {
    int tt = i >> 4, dd = i & 15;
    int t = t0 + tt - 3;
    xs[tt][dd] = (t >= 0 && t < L_TOK) ? xz[(size_t)t*(2*DI) + d0 + dd] : 0.0f;
  }
  for (int i = tid; i < CLEN*XDBL_N; i += 256) {
    int tt = i / XDBL_N, c = i % XDBL_N;
    int t = t0 + tt;
    float v = (t < L_TOK) ? xdbl[(size_t)t*XDBL_N + c] : 0.0f;
    if (c < 12) xd12[tt][c] = v;
    else if (c < 28) bs[tt][c-12] = v;
    else if (p3) cs[tt][c-28] = v;
  }
  if (p3) {
    for (int i = tid; i < CLEN*16; i += 256) {
      int tt = i >> 4, dd = i & 15;
      int t = t0 + tt;
      zs[tt][dd] = (t < L_TOK) ? xz[(size_t)t*(2*DI) + DI + d0 + dd] : 0.0f;
    }
  }
  if (tid < 192) wdt[tid/12][tid%12] = W_dt[(d0 + tid/12)*DTR + tid%12];
  if (tid < 64)  wcs[tid>>2][tid&3]  = Wc[(d0 + (tid>>2))*DCONV + (tid&3)];
  if (tid < 16)  { bds[tid] = b_dt[d0+tid]; bcs[tid] = bc[d0+tid]; }
  __syncthreads();
  for (int i = tid; i < CLEN*16; i += 256) {
    int tt = i >> 4, dd = i & 15;
    float u = bcs[dd];
#pragma unroll
    for (int j = 0; j < 4; ++j) u = fmaf(xs[tt+j][dd], wcs[dd][j], u);
    us[tt][dd] = u / (1.0f + expf(-u));
    float v = bds[dd];
#pragma unroll
    for (int r = 0; r < 12; ++r) v = fmaf(xd12[tt][r], wdt[dd][r], v);
    ds[tt][dd] = (v > 20.0f) ? v : log1pf(expf(v));
  }
  __syncthreads();
}

__global__ __launch_bounds__(256) void scan_p1(
    const float* __restrict__ xz, const float* __restrict__ xdbl,
    const float* __restrict__ Wc, const float* __restrict__ bc,
    const float* __restrict__ W_dt, const float* __restrict__ b_dt,
    const float* __restrict__ A_log,
    float* __restrict__ cP, float* __restrict__ cS) {
  __shared__ float xs[CLEN+3][16], us[CLEN][16], ds[CLEN][16], bs[CLEN][16];
  __shared__ float xd12[CLEN][12], wdt[16][12], wcs[16][4], bds[16], bcs[16];
  int dl = threadIdx.x >> 4, n = threadIdx.x & 15;
  int d0 = blockIdx.x * 16;
  int t0 = blockIdx.y * CLEN;
  int nt = min(CLEN, L_TOK - t0);
  scan_stage_common(xz, xdbl, Wc, bc, W_dt, b_dt, d0, t0,
                    xs, us, ds, bs, xd12, wdt, wcs, bds, bcs,
                    nullptr ? us : us /*unused*/, us /*unused*/, false);
  int d = d0 + dl;
  float a2 = -expf(A_log[d*DS + n]) * 1.44269504088896340736f;
  float s = 0.0f, P = 1.0f;
  for (int tt = 0; tt < nt; ++tt) {
    float dlt = ds[tt][dl], uu = us[tt][dl], Bv = bs[tt][n];
    float dA = exp2f(dlt * a2);
    s = fmaf(dA, s, dlt * Bv * uu);
    P *= dA;
  }
  int o = (blockIdx.y * DI + d) * DS + n;
  cP[o] = P;
  cS[o] = s;
}

// Phase 2: chunk-carry scan. 6144 independent (d,n) recurrences over 25 chunks.
__global__ __launch_bounds__(256) void scan_p2(
    const float* __restrict__ cP, const float* __restrict__ cS,
    float* __restrict__ cIn) {
  int idx = blockIdx.x * 256 + threadIdx.x;
  float in = 0.0f;
  for (int c = 0; c < NCHUNK; ++c) {
    int o = c * (DI*DS) + idx;
    cIn[o] = in;
    in = fmaf(cP[o], in, cS[o]);
  }
}

// Phase 3: re-scan with carry-in, emit y fused with u*Dp and silu(z) gate.
__global__ __launch_bounds__(256) void scan_p3(
    const float* __restrict__ xz, const float* __restrict__ xdbl,
    const float* __restrict__ Wc, const float* __restrict__ bc,
    const float* __restrict__ W_dt, const float* __restrict__ b_dt,
    const float* __restrict__ A_log, const float* __restrict__ Dp,
    const float* __restrict__ cIn, float* __restrict__ yy) {
  __shared__ float xs[CLEN+3][16], us[CLEN][16], ds[CLEN][16], bs[CLEN][16];
  __shared__ float cs[CLEN][16], zs[CLEN][16];
  __shared__ float xd12[CLEN][12], wdt[16][12], wcs[16][4], bds[16], bcs[16];
  int dl = threadIdx.x >> 4, n = threadIdx.x & 15;
  int d0 = blockIdx.x * 16;
  int t0 = blockIdx.y * CLEN;
  int nt = min(CLEN, L_TOK - t0);
  scan_stage_common(xz, xdbl, Wc, bc, W_dt, b_dt, d0, t0,
                    xs, us, ds, bs, xd12, wdt, wcs, bds, bcs,
                    cs, zs, true);
  int d = d0 + dl;
  float a2 = -expf(A_log[d*DS + n]) * 1.44269504088896340736f;
  float s = cIn[(blockIdx.y * DI + d) * DS + n];
  float dpv = Dp[d];
  for (int tt = 0; tt < nt; ++tt) {
    float dlt = ds[tt][dl], uu = us[tt][dl], Bv = bs[tt][n];
    float dA = exp2f(dlt * a2);
    s = fmaf(dA, s, dlt * Bv * uu);
    float p = s * cs[tt][n];
    p += __shfl_xor(p, 1, 64);
    p += __shfl_xor(p, 2, 64);
    p += __shfl_xor(p, 4, 64);
    p += __shfl_xor(p, 8, 64);
    if (n == 0) {
      float z = zs[tt][dl];
      float y = fmaf(uu, dpv, p);
      y *= z / (1.0f + expf(-z));
      yy[(size_t)(t0 + tt)*DI + d] = y;
    }
  }
}

// ---------------------------------------------------------------------------
extern "C" void kernel_launch(void* const* d_in, const int* in_sizes, int n_in,
                              void* d_out, int out_size, void* d_ws, size_t ws_size,
                              hipStream_t stream) {
  const float* x       = (const float*)d_in[0];
  const float* patch_w = (const float*)d_in[1];
  const float* patch_b = (const float*)d_in[2];
  const float* cls_tok = (const float*)d_in[3];
  const float* pos_emb = (const float*)d_in[4];
  const float* ln_g    = (const float*)d_in[5];
  const float* ln_b    = (const float*)d_in[6];
  const float* W_in    = (const float*)d_in[7];
  const float* Wc      = (const float*)d_in[8];
  const float* bc      = (const float*)d_in[9];
  const float* Wx      = (const float*)d_in[10];
  const float* W_dt    = (const float*)d_in[11];
  const float* b_dt    = (const float*)d_in[12];
  const float* A_log   = (const float*)d_in[13];
  const float* Dp      = (const float*)d_in[14];
  const float* W_out   = (const float*)d_in[15];
  const float* fn_g    = (const float*)d_in[16];
  const float* fn_b    = (const float*)d_in[17];

  float* ws = (float*)d_ws;
  float* cur   = ws;                       // 1569*192
  float* h     = cur   + L_TOK*DM;         // 1569*192
  float* xz    = h     + L_TOK*DM;         // 1569*768 (aliases px)
  float* xdbl  = xz    + L_TOK*2*DI;       // 1569*44
  float* yy    = xdbl  + L_TOK*XDBL_N;     // 1569*384
  float* cP    = yy    + L_TOK*DI;         // 25*6144
  float* cS    = cP    + NCHUNK*DI*DS;
  float* cIn   = cS    + NCHUNK*DI*DS;
  float* px    = xz;                       // im2col buffer, dead before layer 0's xz

  // patch embed = im2col + GEMM (M=1568, N=192, K=768) + bias + pos
  im2col_kernel<<<(NPATCH*192 + 255)/256, 256, 0, stream>>>(x, cls_tok, pos_emb, px, cur);
  {
    dim3 grid((DM + 63)/64, (NPATCH + 63)/64);
    gemm2_kernel<<<grid, 256, 0, stream>>>(px, 768, patch_w, 768, cur + DM, DM,
                                           NPATCH, DM, 768, patch_b, pos_emb + DM, 3);
  }

  for (int dep = 0; dep < DEPTH; ++dep) {
    const float* g     = ln_g  + dep*DM;
    const float* bb    = ln_b  + dep*DM;
    const float* Win_l = W_in  + (size_t)dep*2*DI*DM;
    const float* Wc_l  = Wc    + (size_t)dep*DI*DCONV;
    const float* bc_l  = bc    + (size_t)dep*DI;
    const float* Wx_l  = Wx    + (size_t)dep*XDBL_N*DI;
    const float* Wdt_l = W_dt  + (size_t)dep*DI*DTR;
    const float* bdt_l = b_dt  + (size_t)dep*DI;
    const float* Alog_l= A_log + (size_t)dep*DI*DS;
    const float* Dp_l  = Dp    + (size_t)dep*DI;
    const float* Wout_l= W_out + (size_t)dep*DM*DI;

    // h = LN(cur)
    ln_kernel<<<L_TOK, 64, 0, stream>>>(cur, h, g, bb);

    // xz = h @ W_in^T : M=1569, N=768, K=192
    {
      dim3 grid((2*DI + 63)/64, (L_TOK + 63)/64);
      gemm2_kernel<<<grid, 256, 0, stream>>>(h, DM, Win_l, DM, xz, 2*DI,
                                             L_TOK, 2*DI, DM, nullptr, nullptr, 0);
    }

    // xdbl = silu(conv(u)) @ Wx^T : M=1569, N=44, K=384 (conv fused in staging)
    {
      dim3 grid(1, (L_TOK + 63)/64);
      gemm_conv_kernel<<<grid, 256, 0, stream>>>(xz, Wc_l, bc_l, Wx_l, xdbl);
    }

    // selective scan (3-phase chunked; conv+delta recomputed in-block)
    {
      dim3 g1(DI/16, NCHUNK);
      scan_p1<<<g1, 256, 0, stream>>>(xz, xdbl, Wc_l, bc_l, Wdt_l, bdt_l, Alog_l, cP, cS);
      scan_p2<<<(DI*DS)/256, 256, 0, stream>>>(cP, cS, cIn);
      scan_p3<<<g1, 256, 0, stream>>>(xz, xdbl, Wc_l, bc_l, Wdt_l, bdt_l, Alog_l,
                                      Dp_l, cIn, yy);
    }

    // cur += yy @ W_out^T : M=1569, N=192, K=384
    {
      dim3 grid((DM + 63)/64, (L_TOK + 63)/64);
      gemm2_kernel<<<grid, 256, 0, stream>>>(yy, DI, Wout_l, DI, cur, DM,
                                             L_TOK, DM, DI, nullptr, nullptr, 2);
    }
  }

  // final LN -> d_out
  ln_kernel<<<L_TOK, 64, 0, stream>>>(cur, (float*)d_out, fn_g, fn_b);
}

// Round 3
// 1278.225 us; speedup vs baseline: 1.0340x; 1.0340x over previous
//
#include <hip/hip_runtime.h>
#include <hip/hip_bf16.h>
#include <math.h>

#define L_TOK 1569
#define DM 192
#define DI 384
#define DS 16
#define DTR 12
#define DCONV 4
#define XDBL_N (DTR + 2*DS)   // 44
#define DEPTH 8
#define NCHUNK 25
#define CLEN 64
#define NPATCH 1568

typedef __attribute__((ext_vector_type(8))) short short8;
typedef __attribute__((ext_vector_type(4))) float f32x4;

__device__ __forceinline__ unsigned short f2bf(float f) {
  unsigned int u = __float_as_uint(f);
  u += 0x7FFFu + ((u >> 16) & 1u);   // round-to-nearest-even
  return (unsigned short)(u >> 16);
}

// ---------------------------------------------------------------------------
// im2col: px[patch][k] = x[c][t][h*16+p][w*16+q], k = c*256+p*16+q.
// Also writes token 0 (cls + pos).
// ---------------------------------------------------------------------------
__global__ __launch_bounds__(256) void im2col_kernel(
    const float* __restrict__ x, const float* __restrict__ cls,
    const float* __restrict__ pos, float* __restrict__ px,
    float* __restrict__ tok0) {
  if (blockIdx.x == 0 && threadIdx.x < DM)
    tok0[threadIdx.x] = cls[threadIdx.x] + pos[threadIdx.x];
  int gid = blockIdx.x * 256 + threadIdx.x;
  if (gid >= NPATCH * 192) return;      // 192 float4 per patch
  int patch = gid / 192;
  int r = gid % 192;
  int c = r / 64;
  int p = (r >> 2) & 15;
  int q = (r & 3) * 4;
  int t = patch / 196, hw = patch % 196, hh = hw / 14, w = hw % 14;
  const float* src = x + ((size_t)(c*8 + t)*224 + hh*16 + p)*224 + w*16 + q;
  *(float4*)(px + (size_t)patch*768 + r*4) = *(const float4*)src;
}

// ---------------------------------------------------------------------------
// LayerNorm over 192 features. One wave per token, 3 elems/lane.
// ---------------------------------------------------------------------------
__global__ __launch_bounds__(64) void ln_kernel(
    const float* __restrict__ in, float* __restrict__ out,
    const float* __restrict__ g, const float* __restrict__ b) {
  int tokn = blockIdx.x;
  int lane = threadIdx.x;
  const float* row = in + (size_t)tokn*DM;
  float x0 = row[lane], x1 = row[lane+64], x2 = row[lane+128];
  float s = x0 + x1 + x2;
  float s2 = x0*x0 + x1*x1 + x2*x2;
#pragma unroll
  for (int off = 1; off < 64; off <<= 1) {
    s  += __shfl_xor(s,  off, 64);
    s2 += __shfl_xor(s2, off, 64);
  }
  float m = s * (1.0f/192.0f);
  float v = s2 * (1.0f/192.0f) - m*m;
  float rs = rsqrtf(v + 1e-5f);
  float* orow = out + (size_t)tokn*DM;
  orow[lane]     = (x0 - m)*rs*g[lane]     + b[lane];
  orow[lane+64]  = (x1 - m)*rs*g[lane+64]  + b[lane+64];
  orow[lane+128] = (x2 - m)*rs*g[lane+128] + b[lane+128];
}

// ---------------------------------------------------------------------------
// MFMA bf16 GEMM: C[M,N] = A[M,K] * B[N,K]^T, K % 32 == 0.
// fp32 inputs converted to bf16 in staging; fp32 accumulate.
// BM=BN=64, BK=32, 256 threads = 4 waves, each wave owns a 32x32 quadrant.
// LDS rows padded to 40 bf16 (80 B) -> bank stride 20 -> 2-way (free).
// epi: 0 = (+bias), 2 = C += v (residual), 3 = +bias +add[m*ldc+n]
// ---------------------------------------------------------------------------
__global__ __launch_bounds__(256) void mgemm_kernel(
    const float* __restrict__ A, int lda,
    const float* __restrict__ B, int ldb,
    float* __restrict__ C, int ldc,
    int M, int N, int K,
    const float* __restrict__ bias,
    const float* __restrict__ add, int epi) {
  __shared__ unsigned short As[64*40];
  __shared__ unsigned short Bs[64*40];
  int tid = threadIdx.x;
  int m0 = blockIdx.y * 64, n0 = blockIdx.x * 64;
  int wave = tid >> 6, lane = tid & 63;
  int wr = wave >> 1, wc = wave & 1;
  int srow = tid >> 2;          // 0..63
  int skq  = (tid & 3) * 8;     // 0,8,16,24
  f32x4 acc[2][2];
#pragma unroll
  for (int i = 0; i < 2; ++i)
#pragma unroll
    for (int j = 0; j < 2; ++j) acc[i][j] = (f32x4){0.f,0.f,0.f,0.f};

  int am = m0 + srow;
  int bn = n0 + srow;
  bool a_ok = (am < M), b_ok = (bn < N);
  const float* ap = A + (size_t)am*lda + skq;
  const float* bp = B + (size_t)bn*ldb + skq;
  const float4 z4 = {0.f,0.f,0.f,0.f};
  int l15 = lane & 15, lk = (lane >> 4) * 8;

  for (int k0 = 0; k0 < K; k0 += 32) {
    {
      float4 a0 = a_ok ? *(const float4*)(ap + k0)     : z4;
      float4 a1 = a_ok ? *(const float4*)(ap + k0 + 4) : z4;
      float4 b0 = b_ok ? *(const float4*)(bp + k0)     : z4;
      float4 b1 = b_ok ? *(const float4*)(bp + k0 + 4) : z4;
      short8 pa, pb;
      pa[0]=f2bf(a0.x); pa[1]=f2bf(a0.y); pa[2]=f2bf(a0.z); pa[3]=f2bf(a0.w);
      pa[4]=f2bf(a1.x); pa[5]=f2bf(a1.y); pa[6]=f2bf(a1.z); pa[7]=f2bf(a1.w);
      pb[0]=f2bf(b0.x); pb[1]=f2bf(b0.y); pb[2]=f2bf(b0.z); pb[3]=f2bf(b0.w);
      pb[4]=f2bf(b1.x); pb[5]=f2bf(b1.y); pb[6]=f2bf(b1.z); pb[7]=f2bf(b1.w);
      *(short8*)&As[srow*40 + skq] = pa;
      *(short8*)&Bs[srow*40 + skq] = pb;
    }
    __syncthreads();
    short8 af0 = *(const short8*)&As[(wr*32      + l15)*40 + lk];
    short8 af1 = *(const short8*)&As[(wr*32 + 16 + l15)*40 + lk];
    short8 bf0 = *(const short8*)&Bs[(wc*32      + l15)*40 + lk];
    short8 bf1 = *(const short8*)&Bs[(wc*32 + 16 + l15)*40 + lk];
    acc[0][0] = __builtin_amdgcn_mfma_f32_16x16x32_bf16(af0, bf0, acc[0][0], 0, 0, 0);
    acc[0][1] = __builtin_amdgcn_mfma_f32_16x16x32_bf16(af0, bf1, acc[0][1], 0, 0, 0);
    acc[1][0] = __builtin_amdgcn_mfma_f32_16x16x32_bf16(af1, bf0, acc[1][0], 0, 0, 0);
    acc[1][1] = __builtin_amdgcn_mfma_f32_16x16x32_bf16(af1, bf1, acc[1][1], 0, 0, 0);
    __syncthreads();
  }

#pragma unroll
  for (int r = 0; r < 2; ++r) {
#pragma unroll
    for (int c = 0; c < 2; ++c) {
      int col = n0 + wc*32 + c*16 + l15;
      if (col >= N) continue;
      int rowb = m0 + wr*32 + r*16 + (lane >> 4)*4;
      float bv = bias ? bias[col] : 0.0f;
#pragma unroll
      for (int j = 0; j < 4; ++j) {
        int row = rowb + j;
        if (row >= M) continue;
        float v = acc[r][c][j] + bv;
        if (epi == 3) v += add[(size_t)row*ldc + col];
        float* cp = C + (size_t)row*ldc + col;
        if (epi == 2) v += *cp;
        *cp = v;
      }
    }
  }
}

// ---------------------------------------------------------------------------
// Causal depthwise conv (4 taps) + SiLU. u lives in xz[:, 0:384].
// ---------------------------------------------------------------------------
__global__ __launch_bounds__(256) void conv_silu_kernel(
    const float* __restrict__ xz, const float* __restrict__ Wc,
    const float* __restrict__ bc, float* __restrict__ uc) {
  int idx = blockIdx.x * 256 + threadIdx.x;
  if (idx >= L_TOK * DI) return;
  int t = idx / DI, c = idx % DI;
  float acc = bc[c];
#pragma unroll
  for (int k = 0; k < DCONV; ++k) {
    int tt = t - (DCONV - 1) + k;
    if (tt >= 0) acc = fmaf(xz[(size_t)tt*2*DI + c], Wc[c*DCONV + k], acc);
  }
  uc[idx] = acc / (1.0f + expf(-acc));
}

// ---------------------------------------------------------------------------
// Selective scan. conv+SiLU and delta = softplus(xdbl[:, :12] @ W_dt^T + b_dt)
// recomputed in-block from xz / xdbl.
// ---------------------------------------------------------------------------
__device__ __forceinline__ void scan_stage_common(
    const float* __restrict__ xz, const float* __restrict__ xdbl,
    const float* __restrict__ Wc, const float* __restrict__ bc,
    const float* __restrict__ W_dt, const float* __restrict__ b_dt,
    int d0, int t0,
    float xs[CLEN+3][16], float us[CLEN][16], float ds[CLEN][16],
    float bs[CLEN][16], float xd12[CLEN][12],
    float wdt[16][12], float wcs[16][4], float bds[16], float bcs[16],
    float cs[CLEN][16], float zs[CLEN][16], bool p3) {
  int tid = threadIdx.x;
  for (int i = tid; i < (CLEN+3)*16; i += 256) {
    int tt = i >> 4, dd = i & 15;
    int t = t0 + tt - 3;
    xs[tt][dd] = (t >= 0 && t < L_TOK) ? xz[(size_t)t*(2*DI) + d0 + dd] : 0.0f;
  }
  for (int i = tid; i < CLEN*XDBL_N; i += 256) {
    int tt = i / XDBL_N, c = i % XDBL_N;
    int t = t0 + tt;
    float v = (t < L_TOK) ? xdbl[(size_t)t*XDBL_N + c] : 0.0f;
    if (c < 12) xd12[tt][c] = v;
    else if (c < 28) bs[tt][c-12] = v;
    else if (p3) cs[tt][c-28] = v;
  }
  if (p3) {
    for (int i = tid; i < CLEN*16; i += 256) {
      int tt = i >> 4, dd = i & 15;
      int t = t0 + tt;
      zs[tt][dd] = (t < L_TOK) ? xz[(size_t)t*(2*DI) + DI + d0 + dd] : 0.0f;
    }
  }
  if (tid < 192) wdt[tid/12][tid%12] = W_dt[(d0 + tid/12)*DTR + tid%12];
  if (tid < 64)  wcs[tid>>2][tid&3]  = Wc[(d0 + (tid>>2))*DCONV + (tid&3)];
  if (tid < 16)  { bds[tid] = b_dt[d0+tid]; bcs[tid] = bc[d0+tid]; }
  __syncthreads();
  for (int i = tid; i < CLEN*16; i += 256) {
    int tt = i >> 4, dd = i & 15;
    float u = bcs[dd];
#pragma unroll
    for (int j = 0; j < 4; ++j) u = fmaf(xs[tt+j][dd], wcs[dd][j], u);
    us[tt][dd] = u / (1.0f + expf(-u));
    float v = bds[dd];
#pragma unroll
    for (int r = 0; r < 12; ++r) v = fmaf(xd12[tt][r], wdt[dd][r], v);
    ds[tt][dd] = (v > 20.0f) ? v : log1pf(expf(v));
  }
  __syncthreads();
}

__global__ __launch_bounds__(256) void scan_p1(
    const float* __restrict__ xz, const float* __restrict__ xdbl,
    const float* __restrict__ Wc, const float* __restrict__ bc,
    const float* __restrict__ W_dt, const float* __restrict__ b_dt,
    const float* __restrict__ A_log,
    float* __restrict__ cP, float* __restrict__ cS) {
  __shared__ float xs[CLEN+3][16], us[CLEN][16], ds[CLEN][16], bs[CLEN][16];
  __shared__ float xd12[CLEN][12], wdt[16][12], wcs[16][4], bds[16], bcs[16];
  int dl = threadIdx.x >> 4, n = threadIdx.x & 15;
  int d0 = blockIdx.x * 16;
  int t0 = blockIdx.y * CLEN;
  int nt = min(CLEN, L_TOK - t0);
  scan_stage_common(xz, xdbl, Wc, bc, W_dt, b_dt, d0, t0,
                    xs, us, ds, bs, xd12, wdt, wcs, bds, bcs,
                    us, us, false);
  int d = d0 + dl;
  float a2 = -expf(A_log[d*DS + n]) * 1.44269504088896340736f;
  float s = 0.0f, P = 1.0f;
  for (int tt = 0; tt < nt; ++tt) {
    float dlt = ds[tt][dl], uu = us[tt][dl], Bv = bs[tt][n];
    float dA = exp2f(dlt * a2);
    s = fmaf(dA, s, dlt * Bv * uu);
    P *= dA;
  }
  int o = (blockIdx.y * DI + d) * DS + n;
  cP[o] = P;
  cS[o] = s;
}

__global__ __launch_bounds__(256) void scan_p2(
    const float* __restrict__ cP, const float* __restrict__ cS,
    float* __restrict__ cIn) {
  int idx = blockIdx.x * 256 + threadIdx.x;
  float in = 0.0f;
  for (int c = 0; c < NCHUNK; ++c) {
    int o = c * (DI*DS) + idx;
    cIn[o] = in;
    in = fmaf(cP[o], in, cS[o]);
  }
}

__global__ __launch_bounds__(256) void scan_p3(
    const float* __restrict__ xz, const float* __restrict__ xdbl,
    const float* __restrict__ Wc, const float* __restrict__ bc,
    const float* __restrict__ W_dt, const float* __restrict__ b_dt,
    const float* __restrict__ A_log, const float* __restrict__ Dp,
    const float* __restrict__ cIn, float* __restrict__ yy) {
  __shared__ float xs[CLEN+3][16], us[CLEN][16], ds[CLEN][16], bs[CLEN][16];
  __shared__ float cs[CLEN][16], zs[CLEN][16];
  __shared__ float xd12[CLEN][12], wdt[16][12], wcs[16][4], bds[16], bcs[16];
  int dl = threadIdx.x >> 4, n = threadIdx.x & 15;
  int d0 = blockIdx.x * 16;
  int t0 = blockIdx.y * CLEN;
  int nt = min(CLEN, L_TOK - t0);
  scan_stage_common(xz, xdbl, Wc, bc, W_dt, b_dt, d0, t0,
                    xs, us, ds, bs, xd12, wdt, wcs, bds, bcs,
                    cs, zs, true);
  int d = d0 + dl;
  float a2 = -expf(A_log[d*DS + n]) * 1.44269504088896340736f;
  float s = cIn[(blockIdx.y * DI + d) * DS + n];
  float dpv = Dp[d];
  for (int tt = 0; tt < nt; ++tt) {
    float dlt = ds[tt][dl], uu = us[tt][dl], Bv = bs[tt][n];
    float dA = exp2f(dlt * a2);
    s = fmaf(dA, s, dlt * Bv * uu);
    float p = s * cs[tt][n];
    p += __shfl_xor(p, 1, 64);
    p += __shfl_xor(p, 2, 64);
    p += __shfl_xor(p, 4, 64);
    p += __shfl_xor(p, 8, 64);
    if (n == 0) {
      float z = zs[tt][dl];
      float y = fmaf(uu, dpv, p);
      y *= z / (1.0f + expf(-z));
      yy[(size_t)(t0 + tt)*DI + d] = y;
    }
  }
}

// ---------------------------------------------------------------------------
extern "C" void kernel_launch(void* const* d_in, const int* in_sizes, int n_in,
                              void* d_out, int out_size, void* d_ws, size_t ws_size,
                              hipStream_t stream) {
  const float* x       = (const float*)d_in[0];
  const float* patch_w = (const float*)d_in[1];
  const float* patch_b = (const float*)d_in[2];
  const float* cls_tok = (const float*)d_in[3];
  const float* pos_emb = (const float*)d_in[4];
  const float* ln_g    = (const float*)d_in[5];
  const float* ln_b    = (const float*)d_in[6];
  const float* W_in    = (const float*)d_in[7];
  const float* Wc      = (const float*)d_in[8];
  const float* bc      = (const float*)d_in[9];
  const float* Wx      = (const float*)d_in[10];
  const float* W_dt    = (const float*)d_in[11];
  const float* b_dt    = (const float*)d_in[12];
  const float* A_log   = (const float*)d_in[13];
  const float* Dp      = (const float*)d_in[14];
  const float* W_out   = (const float*)d_in[15];
  const float* fn_g    = (const float*)d_in[16];
  const float* fn_b    = (const float*)d_in[17];

  float* ws = (float*)d_ws;
  float* cur   = ws;                       // 1569*192
  float* h     = cur   + L_TOK*DM;         // 1569*192
  float* xz    = h     + L_TOK*DM;         // 1569*768 (aliases px)
  float* uc    = xz    + L_TOK*2*DI;       // 1569*384
  float* xdbl  = uc    + L_TOK*DI;         // 1569*44
  float* yy    = xdbl  + L_TOK*XDBL_N;     // 1569*384
  float* cP    = yy    + L_TOK*DI;         // 25*6144
  float* cS    = cP    + NCHUNK*DI*DS;
  float* cIn   = cS    + NCHUNK*DI*DS;
  float* px    = xz;                       // im2col buffer, dead before layer 0's xz

  // patch embed = im2col + GEMM (M=1568, N=192, K=768) + bias + pos
  im2col_kernel<<<(NPATCH*192 + 255)/256, 256, 0, stream>>>(x, cls_tok, pos_emb, px, cur);
  {
    dim3 grid((DM + 63)/64, (NPATCH + 63)/64);
    mgemm_kernel<<<grid, 256, 0, stream>>>(px, 768, patch_w, 768, cur + DM, DM,
                                           NPATCH, DM, 768, patch_b, pos_emb + DM, 3);
  }

  for (int dep = 0; dep < DEPTH; ++dep) {
    const float* g     = ln_g  + dep*DM;
    const float* bb    = ln_b  + dep*DM;
    const float* Win_l = W_in  + (size_t)dep*2*DI*DM;
    const float* Wc_l  = Wc    + (size_t)dep*DI*DCONV;
    const float* bc_l  = bc    + (size_t)dep*DI;
    const float* Wx_l  = Wx    + (size_t)dep*XDBL_N*DI;
    const float* Wdt_l = W_dt  + (size_t)dep*DI*DTR;
    const float* bdt_l = b_dt  + (size_t)dep*DI;
    const float* Alog_l= A_log + (size_t)dep*DI*DS;
    const float* Dp_l  = Dp    + (size_t)dep*DI;
    const float* Wout_l= W_out + (size_t)dep*DM*DI;

    // h = LN(cur)
    ln_kernel<<<L_TOK, 64, 0, stream>>>(cur, h, g, bb);

    // xz = h @ W_in^T : M=1569, N=768, K=192
    {
      dim3 grid((2*DI + 63)/64, (L_TOK + 63)/64);
      mgemm_kernel<<<grid, 256, 0, stream>>>(h, DM, Win_l, DM, xz, 2*DI,
                                             L_TOK, 2*DI, DM, nullptr, nullptr, 0);
    }

    // uc = silu(causal_conv(u))
    conv_silu_kernel<<<(L_TOK*DI + 255)/256, 256, 0, stream>>>(xz, Wc_l, bc_l, uc);

    // xdbl = uc @ Wx^T : M=1569, N=44, K=384
    {
      dim3 grid(1, (L_TOK + 63)/64);
      mgemm_kernel<<<grid, 256, 0, stream>>>(uc, DI, Wx_l, DI, xdbl, XDBL_N,
                                             L_TOK, XDBL_N, DI, nullptr, nullptr, 0);
    }

    // selective scan (3-phase chunked; conv+delta recomputed in-block)
    {
      dim3 g1(DI/16, NCHUNK);
      scan_p1<<<g1, 256, 0, stream>>>(xz, xdbl, Wc_l, bc_l, Wdt_l, bdt_l, Alog_l, cP, cS);
      scan_p2<<<(DI*DS)/256, 256, 0, stream>>>(cP, cS, cIn);
      scan_p3<<<g1, 256, 0, stream>>>(xz, xdbl, Wc_l, bc_l, Wdt_l, bdt_l, Alog_l,
                                      Dp_l, cIn, yy);
    }

    // cur += yy @ W_out^T : M=1569, N=192, K=384
    {
      dim3 grid((DM + 63)/64, (L_TOK + 63)/64);
      mgemm_kernel<<<grid, 256, 0, stream>>>(yy, DI, Wout_l, DI, cur, DM,
                                             L_TOK, DM, DI, nullptr, nullptr, 2);
    }
  }

  // final LN -> d_out
  ln_kernel<<<L_TOK, 64, 0, stream>>>(cur, (float*)d_out, fn_g, fn_b);
}

// Round 4
// 899.900 us; speedup vs baseline: 1.4687x; 1.4204x over previous
//
#include <hip/hip_runtime.h>
#include <hip/hip_bf16.h>
#include <math.h>

#define L_TOK 1569
#define DM 192
#define DI 384
#define DS 16
#define DTR 12
#define DCONV 4
#define XDBL_N (DTR + 2*DS)   // 44
#define DEPTH 8
#define NCHUNK 25
#define CLEN 64
#define NPATCH 1568

typedef __attribute__((ext_vector_type(8))) short short8;
typedef __attribute__((ext_vector_type(4))) float f32x4;

__device__ __forceinline__ unsigned short f2bf(float f) {
  unsigned int u = __float_as_uint(f);
  u += 0x7FFFu + ((u >> 16) & 1u);   // round-to-nearest-even
  return (unsigned short)(u >> 16);
}

// ---------------------------------------------------------------------------
// im2col + cur init: px[patch][k] = x[c][t][h*16+p][w*16+q], k = c*256+p*16+q.
// Also initializes cur[tok][e] = pos[tok][e] + (tok==0 ? cls[e] : patch_b[e])
// so the split-K patch GEMM can pure-atomicAdd into it.
// ---------------------------------------------------------------------------
__global__ __launch_bounds__(256) void im2col_kernel(
    const float* __restrict__ x, const float* __restrict__ cls,
    const float* __restrict__ pb, const float* __restrict__ pos,
    float* __restrict__ px, float* __restrict__ curp) {
  int gid = blockIdx.x * 256 + threadIdx.x;
  const int initN = (L_TOK * DM) / 4;   // 75312 float4s
  if (gid < initN) {
    int e4 = gid * 4;
    int tok = e4 / DM;
    int col = e4 % DM;
    float4 pv = *(const float4*)(pos + e4);
    float4 av = (tok == 0) ? *(const float4*)(cls + col)
                           : *(const float4*)(pb + col);
    float4 o = {pv.x + av.x, pv.y + av.y, pv.z + av.z, pv.w + av.w};
    *(float4*)(curp + e4) = o;
  }
  if (gid >= NPATCH * 192) return;      // 192 float4 per patch
  int patch = gid / 192;
  int r = gid % 192;
  int c = r / 64;
  int p = (r >> 2) & 15;
  int q = (r & 3) * 4;
  int t = patch / 196, hw = patch % 196, hh = hw / 14, w = hw % 14;
  const float* src = x + ((size_t)(c*8 + t)*224 + hh*16 + p)*224 + w*16 + q;
  *(float4*)(px + (size_t)patch*768 + r*4) = *(const float4*)src;
}

// ---------------------------------------------------------------------------
// LayerNorm over 192 features. One wave per token, 3 elems/lane.
// ---------------------------------------------------------------------------
__global__ __launch_bounds__(64) void ln_kernel(
    const float* __restrict__ in, float* __restrict__ out,
    const float* __restrict__ g, const float* __restrict__ b) {
  int tokn = blockIdx.x;
  int lane = threadIdx.x;
  const float* row = in + (size_t)tokn*DM;
  float x0 = row[lane], x1 = row[lane+64], x2 = row[lane+128];
  float s = x0 + x1 + x2;
  float s2 = x0*x0 + x1*x1 + x2*x2;
#pragma unroll
  for (int off = 1; off < 64; off <<= 1) {
    s  += __shfl_xor(s,  off, 64);
    s2 += __shfl_xor(s2, off, 64);
  }
  float m = s * (1.0f/192.0f);
  float v = s2 * (1.0f/192.0f) - m*m;
  float rs = rsqrtf(v + 1e-5f);
  float* orow = out + (size_t)tokn*DM;
  orow[lane]     = (x0 - m)*rs*g[lane]     + b[lane];
  orow[lane+64]  = (x1 - m)*rs*g[lane+64]  + b[lane+64];
  orow[lane+128] = (x2 - m)*rs*g[lane+128] + b[lane+128];
}

// ---------------------------------------------------------------------------
// MFMA bf16 GEMM with split-K: C[M,N] (+)= A[M,K_slice] * B[N,K_slice]^T.
// grid.z slices K: each block handles ksl = K/KSPLIT cols, ksl % 32 == 0.
// atomic=0: plain store (KSPLIT must be 1). atomic=1: atomicAdd (C pre-init).
// Register prefetch: next tile's global loads issued before MFMA.
// ---------------------------------------------------------------------------
__global__ __launch_bounds__(256) void mgemm_kernel(
    const float* __restrict__ A, int lda,
    const float* __restrict__ B, int ldb,
    float* __restrict__ C, int ldc,
    int M, int N, int ksl, int atomic) {
  __shared__ unsigned short As[64*40];
  __shared__ unsigned short Bs[64*40];
  int tid = threadIdx.x;
  int m0 = blockIdx.y * 64, n0 = blockIdx.x * 64;
  int kbase = blockIdx.z * ksl;
  int wave = tid >> 6, lane = tid & 63;
  int wr = wave >> 1, wc = wave & 1;
  int srow = tid >> 2;          // 0..63
  int skq  = (tid & 3) * 8;     // 0,8,16,24
  f32x4 acc[2][2];
#pragma unroll
  for (int i = 0; i < 2; ++i)
#pragma unroll
    for (int j = 0; j < 2; ++j) acc[i][j] = (f32x4){0.f,0.f,0.f,0.f};

  int am = m0 + srow;
  int bn = n0 + srow;
  bool a_ok = (am < M), b_ok = (bn < N);
  const float* ap = A + (size_t)am*lda + kbase + skq;
  const float* bp = B + (size_t)bn*ldb + kbase + skq;
  const float4 z4 = {0.f,0.f,0.f,0.f};
  int l15 = lane & 15, lk = (lane >> 4) * 8;

  int nt = ksl >> 5;
  float4 a0 = a_ok ? *(const float4*)(ap)     : z4;
  float4 a1 = a_ok ? *(const float4*)(ap + 4) : z4;
  float4 b0 = b_ok ? *(const float4*)(bp)     : z4;
  float4 b1 = b_ok ? *(const float4*)(bp + 4) : z4;

  for (int i = 0; i < nt; ++i) {
    {
      short8 pa, pb;
      pa[0]=f2bf(a0.x); pa[1]=f2bf(a0.y); pa[2]=f2bf(a0.z); pa[3]=f2bf(a0.w);
      pa[4]=f2bf(a1.x); pa[5]=f2bf(a1.y); pa[6]=f2bf(a1.z); pa[7]=f2bf(a1.w);
      pb[0]=f2bf(b0.x); pb[1]=f2bf(b0.y); pb[2]=f2bf(b0.z); pb[3]=f2bf(b0.w);
      pb[4]=f2bf(b1.x); pb[5]=f2bf(b1.y); pb[6]=f2bf(b1.z); pb[7]=f2bf(b1.w);
      *(short8*)&As[srow*40 + skq] = pa;
      *(short8*)&Bs[srow*40 + skq] = pb;
    }
    __syncthreads();
    // prefetch next tile while MFMAs run
    bool pf = (i + 1 < nt);
    int k0n = (i + 1) << 5;
    a0 = (pf && a_ok) ? *(const float4*)(ap + k0n)     : z4;
    a1 = (pf && a_ok) ? *(const float4*)(ap + k0n + 4) : z4;
    b0 = (pf && b_ok) ? *(const float4*)(bp + k0n)     : z4;
    b1 = (pf && b_ok) ? *(const float4*)(bp + k0n + 4) : z4;

    short8 af0 = *(const short8*)&As[(wr*32      + l15)*40 + lk];
    short8 af1 = *(const short8*)&As[(wr*32 + 16 + l15)*40 + lk];
    short8 bf0 = *(const short8*)&Bs[(wc*32      + l15)*40 + lk];
    short8 bf1 = *(const short8*)&Bs[(wc*32 + 16 + l15)*40 + lk];
    acc[0][0] = __builtin_amdgcn_mfma_f32_16x16x32_bf16(af0, bf0, acc[0][0], 0, 0, 0);
    acc[0][1] = __builtin_amdgcn_mfma_f32_16x16x32_bf16(af0, bf1, acc[0][1], 0, 0, 0);
    acc[1][0] = __builtin_amdgcn_mfma_f32_16x16x32_bf16(af1, bf0, acc[1][0], 0, 0, 0);
    acc[1][1] = __builtin_amdgcn_mfma_f32_16x16x32_bf16(af1, bf1, acc[1][1], 0, 0, 0);
    __syncthreads();
  }

#pragma unroll
  for (int r = 0; r < 2; ++r) {
#pragma unroll
    for (int c = 0; c < 2; ++c) {
      int col = n0 + wc*32 + c*16 + l15;
      if (col >= N) continue;
      int rowb = m0 + wr*32 + r*16 + (lane >> 4)*4;
#pragma unroll
      for (int j = 0; j < 4; ++j) {
        int row = rowb + j;
        if (row >= M) continue;
        float v = acc[r][c][j];
        float* cp = C + (size_t)row*ldc + col;
        if (atomic) atomicAdd(cp, v);
        else        *cp = v;
      }
    }
  }
}

// ---------------------------------------------------------------------------
// xdbl GEMM with conv+SiLU fused into A-staging (MFMA + split-K + atomic).
// A[t][d] = silu(bc[d] + sum_j xz[t-3+j][d] * Wc[d][j]); C = A @ Wx^T.
// M=L_TOK, N=44, K=DI. grid = (1, 25, KSPLIT). C must be zero-initialized.
// ---------------------------------------------------------------------------
__global__ __launch_bounds__(256) void cgemm_kernel(
    const float* __restrict__ xz,
    const float* __restrict__ Wc, const float* __restrict__ bc,
    const float* __restrict__ B, float* __restrict__ C, int ksl) {
  __shared__ unsigned short As[64*40];
  __shared__ unsigned short Bs[64*40];
  __shared__ float wcs[96][4];
  __shared__ float bcs[96];
  const int M = L_TOK, N = XDBL_N;
  int tid = threadIdx.x;
  int m0 = blockIdx.y * 64, n0 = 0;
  int kbase = blockIdx.z * ksl;
  int wave = tid >> 6, lane = tid & 63;
  int wr = wave >> 1, wc = wave & 1;
  int srow = tid >> 2;
  int skq  = (tid & 3) * 8;
  f32x4 acc[2][2];
#pragma unroll
  for (int i = 0; i < 2; ++i)
#pragma unroll
    for (int j = 0; j < 2; ++j) acc[i][j] = (f32x4){0.f,0.f,0.f,0.f};

  if (tid < 96) {
    *(float4*)wcs[tid] = *(const float4*)(Wc + (size_t)(kbase + tid)*4);
    bcs[tid] = bc[kbase + tid];
  }

  int t = m0 + srow;
  int bn = n0 + srow;
  bool a_ok = (t < M), b_ok = (bn < N);
  const float* bp = B + (size_t)bn*DI + kbase + skq;
  const float4 z4 = {0.f,0.f,0.f,0.f};
  int l15 = lane & 15, lk = (lane >> 4) * 8;
  __syncthreads();   // wcs/bcs ready

  int nt = ksl >> 5;
  for (int i = 0; i < nt; ++i) {
    int cg = kbase + i*32 + skq;      // channel base for this thread
    int wi = i*32 + skq;              // index into wcs/bcs slice
    // conv taps: rows t-3..t, channels cg..cg+7
    float tap[4][8];
#pragma unroll
    for (int j = 0; j < 4; ++j) {
      int ts = t - 3 + j;
      float4 v0 = z4, v1 = z4;
      if (a_ok && ts >= 0) {
        v0 = *(const float4*)(xz + (size_t)ts*(2*DI) + cg);
        v1 = *(const float4*)(xz + (size_t)ts*(2*DI) + cg + 4);
      }
      tap[j][0]=v0.x; tap[j][1]=v0.y; tap[j][2]=v0.z; tap[j][3]=v0.w;
      tap[j][4]=v1.x; tap[j][5]=v1.y; tap[j][6]=v1.z; tap[j][7]=v1.w;
    }
    float4 bv0 = b_ok ? *(const float4*)(bp + i*32)     : z4;
    float4 bv1 = b_ok ? *(const float4*)(bp + i*32 + 4) : z4;
    short8 pa, pb;
#pragma unroll
    for (int c = 0; c < 8; ++c) {
      float u = bcs[wi + c];
#pragma unroll
      for (int j = 0; j < 4; ++j) u = fmaf(tap[j][c], wcs[wi + c][j], u);
      u = u / (1.0f + expf(-u));
      pa[c] = (short)f2bf(u);
    }
    pb[0]=f2bf(bv0.x); pb[1]=f2bf(bv0.y); pb[2]=f2bf(bv0.z); pb[3]=f2bf(bv0.w);
    pb[4]=f2bf(bv1.x); pb[5]=f2bf(bv1.y); pb[6]=f2bf(bv1.z); pb[7]=f2bf(bv1.w);
    *(short8*)&As[srow*40 + skq] = pa;
    *(short8*)&Bs[srow*40 + skq] = pb;
    __syncthreads();
    short8 af0 = *(const short8*)&As[(wr*32      + l15)*40 + lk];
    short8 af1 = *(const short8*)&As[(wr*32 + 16 + l15)*40 + lk];
    short8 bf0 = *(const short8*)&Bs[(wc*32      + l15)*40 + lk];
    short8 bf1 = *(const short8*)&Bs[(wc*32 + 16 + l15)*40 + lk];
    acc[0][0] = __builtin_amdgcn_mfma_f32_16x16x32_bf16(af0, bf0, acc[0][0], 0, 0, 0);
    acc[0][1] = __builtin_amdgcn_mfma_f32_16x16x32_bf16(af0, bf1, acc[0][1], 0, 0, 0);
    acc[1][0] = __builtin_amdgcn_mfma_f32_16x16x32_bf16(af1, bf0, acc[1][0], 0, 0, 0);
    acc[1][1] = __builtin_amdgcn_mfma_f32_16x16x32_bf16(af1, bf1, acc[1][1], 0, 0, 0);
    __syncthreads();
  }

#pragma unroll
  for (int r = 0; r < 2; ++r) {
#pragma unroll
    for (int c = 0; c < 2; ++c) {
      int col = n0 + wc*32 + c*16 + l15;
      if (col >= N) continue;
      int rowb = m0 + wr*32 + r*16 + (lane >> 4)*4;
#pragma unroll
      for (int j = 0; j < 4; ++j) {
        int row = rowb + j;
        if (row >= M) continue;
        atomicAdd(C + (size_t)row*XDBL_N + col, acc[r][c][j]);
      }
    }
  }
}

// ---------------------------------------------------------------------------
// Selective scan. conv+SiLU and delta = softplus(xdbl[:, :12] @ W_dt^T + b_dt)
// recomputed in-block from xz / xdbl.
// ---------------------------------------------------------------------------
__device__ __forceinline__ void scan_stage_common(
    const float* __restrict__ xz, const float* __restrict__ xdbl,
    const float* __restrict__ Wc, const float* __restrict__ bc,
    const float* __restrict__ W_dt, const float* __restrict__ b_dt,
    int d0, int t0,
    float xs[CLEN+3][16], float us[CLEN][16], float ds[CLEN][16],
    float bs[CLEN][16], float xd12[CLEN][12],
    float wdt[16][12], float wcs[16][4], float bds[16], float bcs[16],
    float cs[CLEN][16], float zs[CLEN][16], bool p3) {
  int tid = threadIdx.x;
  for (int i = tid; i < (CLEN+3)*16; i += 256) {
    int tt = i >> 4, dd = i & 15;
    int t = t0 + tt - 3;
    xs[tt][dd] = (t >= 0 && t < L_TOK) ? xz[(size_t)t*(2*DI) + d0 + dd] : 0.0f;
  }
  for (int i = tid; i < CLEN*XDBL_N; i += 256) {
    int tt = i / XDBL_N, c = i % XDBL_N;
    int t = t0 + tt;
    float v = (t < L_TOK) ? xdbl[(size_t)t*XDBL_N + c] : 0.0f;
    if (c < 12) xd12[tt][c] = v;
    else if (c < 28) bs[tt][c-12] = v;
    else if (p3) cs[tt][c-28] = v;
  }
  if (p3) {
    for (int i = tid; i < CLEN*16; i += 256) {
      int tt = i >> 4, dd = i & 15;
      int t = t0 + tt;
      zs[tt][dd] = (t < L_TOK) ? xz[(size_t)t*(2*DI) + DI + d0 + dd] : 0.0f;
    }
  }
  if (tid < 192) wdt[tid/12][tid%12] = W_dt[(d0 + tid/12)*DTR + tid%12];
  if (tid < 64)  wcs[tid>>2][tid&3]  = Wc[(d0 + (tid>>2))*DCONV + (tid&3)];
  if (tid < 16)  { bds[tid] = b_dt[d0+tid]; bcs[tid] = bc[d0+tid]; }
  __syncthreads();
  for (int i = tid; i < CLEN*16; i += 256) {
    int tt = i >> 4, dd = i & 15;
    float u = bcs[dd];
#pragma unroll
    for (int j = 0; j < 4; ++j) u = fmaf(xs[tt+j][dd], wcs[dd][j], u);
    us[tt][dd] = u / (1.0f + expf(-u));
    float v = bds[dd];
#pragma unroll
    for (int r = 0; r < 12; ++r) v = fmaf(xd12[tt][r], wdt[dd][r], v);
    ds[tt][dd] = (v > 20.0f) ? v : log1pf(expf(v));
  }
  __syncthreads();
}

__global__ __launch_bounds__(256) void scan_p1(
    const float* __restrict__ xz, const float* __restrict__ xdbl,
    const float* __restrict__ Wc, const float* __restrict__ bc,
    const float* __restrict__ W_dt, const float* __restrict__ b_dt,
    const float* __restrict__ A_log,
    float* __restrict__ cP, float* __restrict__ cS) {
  __shared__ float xs[CLEN+3][16], us[CLEN][16], ds[CLEN][16], bs[CLEN][16];
  __shared__ float xd12[CLEN][12], wdt[16][12], wcs[16][4], bds[16], bcs[16];
  int dl = threadIdx.x >> 4, n = threadIdx.x & 15;
  int d0 = blockIdx.x * 16;
  int t0 = blockIdx.y * CLEN;
  int nt = min(CLEN, L_TOK - t0);
  scan_stage_common(xz, xdbl, Wc, bc, W_dt, b_dt, d0, t0,
                    xs, us, ds, bs, xd12, wdt, wcs, bds, bcs,
                    us, us, false);
  int d = d0 + dl;
  float a2 = -expf(A_log[d*DS + n]) * 1.44269504088896340736f;
  float s = 0.0f, P = 1.0f;
  for (int tt = 0; tt < nt; ++tt) {
    float dlt = ds[tt][dl], uu = us[tt][dl], Bv = bs[tt][n];
    float dA = exp2f(dlt * a2);
    s = fmaf(dA, s, dlt * Bv * uu);
    P *= dA;
  }
  int o = (blockIdx.y * DI + d) * DS + n;
  cP[o] = P;
  cS[o] = s;
}

__global__ __launch_bounds__(256) void scan_p2(
    const float* __restrict__ cP, const float* __restrict__ cS,
    float* __restrict__ cIn) {
  int idx = blockIdx.x * 256 + threadIdx.x;
  float in = 0.0f;
  for (int c = 0; c < NCHUNK; ++c) {
    int o = c * (DI*DS) + idx;
    cIn[o] = in;
    in = fmaf(cP[o], in, cS[o]);
  }
}

__global__ __launch_bounds__(256) void scan_p3(
    const float* __restrict__ xz, const float* __restrict__ xdbl,
    const float* __restrict__ Wc, const float* __restrict__ bc,
    const float* __restrict__ W_dt, const float* __restrict__ b_dt,
    const float* __restrict__ A_log, const float* __restrict__ Dp,
    const float* __restrict__ cIn, float* __restrict__ yy) {
  __shared__ float xs[CLEN+3][16], us[CLEN][16], ds[CLEN][16], bs[CLEN][16];
  __shared__ float cs[CLEN][16], zs[CLEN][16];
  __shared__ float xd12[CLEN][12], wdt[16][12], wcs[16][4], bds[16], bcs[16];
  int dl = threadIdx.x >> 4, n = threadIdx.x & 15;
  int d0 = blockIdx.x * 16;
  int t0 = blockIdx.y * CLEN;
  int nt = min(CLEN, L_TOK - t0);
  scan_stage_common(xz, xdbl, Wc, bc, W_dt, b_dt, d0, t0,
                    xs, us, ds, bs, xd12, wdt, wcs, bds, bcs,
                    cs, zs, true);
  int d = d0 + dl;
  float a2 = -expf(A_log[d*DS + n]) * 1.44269504088896340736f;
  float s = cIn[(blockIdx.y * DI + d) * DS + n];
  float dpv = Dp[d];
  for (int tt = 0; tt < nt; ++tt) {
    float dlt = ds[tt][dl], uu = us[tt][dl], Bv = bs[tt][n];
    float dA = exp2f(dlt * a2);
    s = fmaf(dA, s, dlt * Bv * uu);
    float p = s * cs[tt][n];
    p += __shfl_xor(p, 1, 64);
    p += __shfl_xor(p, 2, 64);
    p += __shfl_xor(p, 4, 64);
    p += __shfl_xor(p, 8, 64);
    if (n == 0) {
      float z = zs[tt][dl];
      float y = fmaf(uu, dpv, p);
      y *= z / (1.0f + expf(-z));
      yy[(size_t)(t0 + tt)*DI + d] = y;
    }
  }
}

// ---------------------------------------------------------------------------
extern "C" void kernel_launch(void* const* d_in, const int* in_sizes, int n_in,
                              void* d_out, int out_size, void* d_ws, size_t ws_size,
                              hipStream_t stream) {
  const float* x       = (const float*)d_in[0];
  const float* patch_w = (const float*)d_in[1];
  const float* patch_b = (const float*)d_in[2];
  const float* cls_tok = (const float*)d_in[3];
  const float* pos_emb = (const float*)d_in[4];
  const float* ln_g    = (const float*)d_in[5];
  const float* ln_b    = (const float*)d_in[6];
  const float* W_in    = (const float*)d_in[7];
  const float* Wc      = (const float*)d_in[8];
  const float* bc      = (const float*)d_in[9];
  const float* Wx      = (const float*)d_in[10];
  const float* W_dt    = (const float*)d_in[11];
  const float* b_dt    = (const float*)d_in[12];
  const float* A_log   = (const float*)d_in[13];
  const float* Dp      = (const float*)d_in[14];
  const float* W_out   = (const float*)d_in[15];
  const float* fn_g    = (const float*)d_in[16];
  const float* fn_b    = (const float*)d_in[17];

  float* ws = (float*)d_ws;
  float* cur   = ws;                       // 1569*192
  float* h     = cur   + L_TOK*DM;         // 1569*192
  float* xz    = h     + L_TOK*DM;         // 1569*768 (aliases px)
  float* xdbl  = xz    + L_TOK*2*DI;       // 1569*44
  float* yy    = xdbl  + L_TOK*XDBL_N;     // 1569*384
  float* cP    = yy    + L_TOK*DI;         // 25*6144
  float* cS    = cP    + NCHUNK*DI*DS;
  float* cIn   = cS    + NCHUNK*DI*DS;
  float* px    = xz;                       // im2col buffer, dead before layer 0's xz

  // im2col + cur init (pos + bias/cls)
  im2col_kernel<<<(NPATCH*192 + 255)/256, 256, 0, stream>>>(
      x, cls_tok, patch_b, pos_emb, px, cur);
  // patch GEMM: cur[1..] += px @ patch_w^T, M=1568, N=192, K=768, split-K 4
  {
    dim3 grid(DM/64, (NPATCH + 63)/64, 4);
    mgemm_kernel<<<grid, 256, 0, stream>>>(px, 768, patch_w, 768, cur + DM, DM,
                                           NPATCH, DM, 768/4, 1);
  }

  for (int dep = 0; dep < DEPTH; ++dep) {
    const float* g     = ln_g  + dep*DM;
    const float* bb    = ln_b  + dep*DM;
    const float* Win_l = W_in  + (size_t)dep*2*DI*DM;
    const float* Wc_l  = Wc    + (size_t)dep*DI*DCONV;
    const float* bc_l  = bc    + (size_t)dep*DI;
    const float* Wx_l  = Wx    + (size_t)dep*XDBL_N*DI;
    const float* Wdt_l = W_dt  + (size_t)dep*DI*DTR;
    const float* bdt_l = b_dt  + (size_t)dep*DI;
    const float* Alog_l= A_log + (size_t)dep*DI*DS;
    const float* Dp_l  = Dp    + (size_t)dep*DI;
    const float* Wout_l= W_out + (size_t)dep*DM*DI;

    // h = LN(cur)
    ln_kernel<<<L_TOK, 64, 0, stream>>>(cur, h, g, bb);

    // xz = h @ W_in^T : M=1569, N=768, K=192 (no split, 300 blocks)
    {
      dim3 grid((2*DI)/64, (L_TOK + 63)/64, 1);
      mgemm_kernel<<<grid, 256, 0, stream>>>(h, DM, Win_l, DM, xz, 2*DI,
                                             L_TOK, 2*DI, DM, 0);
    }

    // xdbl = silu(conv(u)) @ Wx^T : M=1569, N=44, K=384, split-K 4, conv fused
    hipMemsetAsync(xdbl, 0, (size_t)L_TOK*XDBL_N*sizeof(float), stream);
    {
      dim3 grid(1, (L_TOK + 63)/64, 4);
      cgemm_kernel<<<grid, 256, 0, stream>>>(xz, Wc_l, bc_l, Wx_l, xdbl, DI/4);
    }

    // selective scan (3-phase chunked; conv+delta recomputed in-block)
    {
      dim3 g1(DI/16, NCHUNK);
      scan_p1<<<g1, 256, 0, stream>>>(xz, xdbl, Wc_l, bc_l, Wdt_l, bdt_l, Alog_l, cP, cS);
      scan_p2<<<(DI*DS)/256, 256, 0, stream>>>(cP, cS, cIn);
      scan_p3<<<g1, 256, 0, stream>>>(xz, xdbl, Wc_l, bc_l, Wdt_l, bdt_l, Alog_l,
                                      Dp_l, cIn, yy);
    }

    // cur += yy @ W_out^T : M=1569, N=192, K=384, split-K 4 (residual via atomic)
    {
      dim3 grid(DM/64, (L_TOK + 63)/64, 4);
      mgemm_kernel<<<grid, 256, 0, stream>>>(yy, DI, Wout_l, DI, cur, DM,
                                             L_TOK, DM, DI/4, 1);
    }
  }

  // final LN -> d_out
  ln_kernel<<<L_TOK, 64, 0, stream>>>(cur, (float*)d_out, fn_g, fn_b);
}

// Round 5
// 887.643 us; speedup vs baseline: 1.4889x; 1.0138x over previous
//
#include <hip/hip_runtime.h>
#include <hip/hip_bf16.h>
#include <math.h>

#define L_TOK 1569
#define DM 192
#define DI 384
#define DS 16
#define DTR 12
#define DCONV 4
#define XDBL_N (DTR + 2*DS)   // 44
#define DEPTH 8
#define NCHUNK 25
#define CLEN 64
#define NPATCH 1568

typedef __attribute__((ext_vector_type(8))) short short8;
typedef __attribute__((ext_vector_type(4))) float f32x4;

__device__ __forceinline__ unsigned short f2bf(float f) {
  unsigned int u = __float_as_uint(f);
  u += 0x7FFFu + ((u >> 16) & 1u);   // round-to-nearest-even
  return (unsigned short)(u >> 16);
}

// ---------------------------------------------------------------------------
// im2col + cur init: px[patch][k] = x[c][t][h*16+p][w*16+q], k = c*256+p*16+q.
// Also initializes cur[tok][e] = pos[tok][e] + (tok==0 ? cls[e] : patch_b[e])
// so the split-K patch GEMM can pure-atomicAdd into it.
// ---------------------------------------------------------------------------
__global__ __launch_bounds__(256) void im2col_kernel(
    const float* __restrict__ x, const float* __restrict__ cls,
    const float* __restrict__ pb, const float* __restrict__ pos,
    float* __restrict__ px, float* __restrict__ curp) {
  int gid = blockIdx.x * 256 + threadIdx.x;
  const int initN = (L_TOK * DM) / 4;   // 75312 float4s
  if (gid < initN) {
    int e4 = gid * 4;
    int tok = e4 / DM;
    int col = e4 % DM;
    float4 pv = *(const float4*)(pos + e4);
    float4 av = (tok == 0) ? *(const float4*)(cls + col)
                           : *(const float4*)(pb + col);
    float4 o = {pv.x + av.x, pv.y + av.y, pv.z + av.z, pv.w + av.w};
    *(float4*)(curp + e4) = o;
  }
  if (gid >= NPATCH * 192) return;      // 192 float4 per patch
  int patch = gid / 192;
  int r = gid % 192;
  int c = r / 64;
  int p = (r >> 2) & 15;
  int q = (r & 3) * 4;
  int t = patch / 196, hw = patch % 196, hh = hw / 14, w = hw % 14;
  const float* src = x + ((size_t)(c*8 + t)*224 + hh*16 + p)*224 + w*16 + q;
  *(float4*)(px + (size_t)patch*768 + r*4) = *(const float4*)src;
}

// ---------------------------------------------------------------------------
// LayerNorm over 192 features. One wave per token, 3 elems/lane.
// Also zeroes the token's row of zbuf (xdbl, 44 floats) when zbuf != nullptr,
// replacing the pathological hipMemsetAsync (runtime fill wrote 256 MB/call).
// ---------------------------------------------------------------------------
__global__ __launch_bounds__(64) void ln_kernel(
    const float* __restrict__ in, float* __restrict__ out,
    const float* __restrict__ g, const float* __restrict__ b,
    float* __restrict__ zbuf) {
  int tokn = blockIdx.x;
  int lane = threadIdx.x;
  if (zbuf && lane < 11) {
    float4 z = {0.f, 0.f, 0.f, 0.f};
    *(float4*)(zbuf + (size_t)tokn*XDBL_N + lane*4) = z;
  }
  const float* row = in + (size_t)tokn*DM;
  float x0 = row[lane], x1 = row[lane+64], x2 = row[lane+128];
  float s = x0 + x1 + x2;
  float s2 = x0*x0 + x1*x1 + x2*x2;
#pragma unroll
  for (int off = 1; off < 64; off <<= 1) {
    s  += __shfl_xor(s,  off, 64);
    s2 += __shfl_xor(s2, off, 64);
  }
  float m = s * (1.0f/192.0f);
  float v = s2 * (1.0f/192.0f) - m*m;
  float rs = rsqrtf(v + 1e-5f);
  float* orow = out + (size_t)tokn*DM;
  orow[lane]     = (x0 - m)*rs*g[lane]     + b[lane];
  orow[lane+64]  = (x1 - m)*rs*g[lane+64]  + b[lane+64];
  orow[lane+128] = (x2 - m)*rs*g[lane+128] + b[lane+128];
}

// ---------------------------------------------------------------------------
// MFMA bf16 GEMM with split-K: C[M,N] (+)= A[M,K_slice] * B[N,K_slice]^T.
// grid.z slices K: each block handles ksl = K/KSPLIT cols, ksl % 32 == 0.
// atomic=0: plain store (KSPLIT must be 1). atomic=1: atomicAdd (C pre-init).
// Register prefetch: next tile's global loads issued before MFMA.
// ---------------------------------------------------------------------------
__global__ __launch_bounds__(256) void mgemm_kernel(
    const float* __restrict__ A, int lda,
    const float* __restrict__ B, int ldb,
    float* __restrict__ C, int ldc,
    int M, int N, int ksl, int atomic) {
  __shared__ unsigned short As[64*40];
  __shared__ unsigned short Bs[64*40];
  int tid = threadIdx.x;
  int m0 = blockIdx.y * 64, n0 = blockIdx.x * 64;
  int kbase = blockIdx.z * ksl;
  int wave = tid >> 6, lane = tid & 63;
  int wr = wave >> 1, wc = wave & 1;
  int srow = tid >> 2;          // 0..63
  int skq  = (tid & 3) * 8;     // 0,8,16,24
  f32x4 acc[2][2];
#pragma unroll
  for (int i = 0; i < 2; ++i)
#pragma unroll
    for (int j = 0; j < 2; ++j) acc[i][j] = (f32x4){0.f,0.f,0.f,0.f};

  int am = m0 + srow;
  int bn = n0 + srow;
  bool a_ok = (am < M), b_ok = (bn < N);
  const float* ap = A + (size_t)am*lda + kbase + skq;
  const float* bp = B + (size_t)bn*ldb + kbase + skq;
  const float4 z4 = {0.f,0.f,0.f,0.f};
  int l15 = lane & 15, lk = (lane >> 4) * 8;

  int nt = ksl >> 5;
  float4 a0 = a_ok ? *(const float4*)(ap)     : z4;
  float4 a1 = a_ok ? *(const float4*)(ap + 4) : z4;
  float4 b0 = b_ok ? *(const float4*)(bp)     : z4;
  float4 b1 = b_ok ? *(const float4*)(bp + 4) : z4;

  for (int i = 0; i < nt; ++i) {
    {
      short8 pa, pb;
      pa[0]=f2bf(a0.x); pa[1]=f2bf(a0.y); pa[2]=f2bf(a0.z); pa[3]=f2bf(a0.w);
      pa[4]=f2bf(a1.x); pa[5]=f2bf(a1.y); pa[6]=f2bf(a1.z); pa[7]=f2bf(a1.w);
      pb[0]=f2bf(b0.x); pb[1]=f2bf(b0.y); pb[2]=f2bf(b0.z); pb[3]=f2bf(b0.w);
      pb[4]=f2bf(b1.x); pb[5]=f2bf(b1.y); pb[6]=f2bf(b1.z); pb[7]=f2bf(b1.w);
      *(short8*)&As[srow*40 + skq] = pa;
      *(short8*)&Bs[srow*40 + skq] = pb;
    }
    __syncthreads();
    // prefetch next tile while MFMAs run
    bool pf = (i + 1 < nt);
    int k0n = (i + 1) << 5;
    a0 = (pf && a_ok) ? *(const float4*)(ap + k0n)     : z4;
    a1 = (pf && a_ok) ? *(const float4*)(ap + k0n + 4) : z4;
    b0 = (pf && b_ok) ? *(const float4*)(bp + k0n)     : z4;
    b1 = (pf && b_ok) ? *(const float4*)(bp + k0n + 4) : z4;

    short8 af0 = *(const short8*)&As[(wr*32      + l15)*40 + lk];
    short8 af1 = *(const short8*)&As[(wr*32 + 16 + l15)*40 + lk];
    short8 bf0 = *(const short8*)&Bs[(wc*32      + l15)*40 + lk];
    short8 bf1 = *(const short8*)&Bs[(wc*32 + 16 + l15)*40 + lk];
    acc[0][0] = __builtin_amdgcn_mfma_f32_16x16x32_bf16(af0, bf0, acc[0][0], 0, 0, 0);
    acc[0][1] = __builtin_amdgcn_mfma_f32_16x16x32_bf16(af0, bf1, acc[0][1], 0, 0, 0);
    acc[1][0] = __builtin_amdgcn_mfma_f32_16x16x32_bf16(af1, bf0, acc[1][0], 0, 0, 0);
    acc[1][1] = __builtin_amdgcn_mfma_f32_16x16x32_bf16(af1, bf1, acc[1][1], 0, 0, 0);
    __syncthreads();
  }

#pragma unroll
  for (int r = 0; r < 2; ++r) {
#pragma unroll
    for (int c = 0; c < 2; ++c) {
      int col = n0 + wc*32 + c*16 + l15;
      if (col >= N) continue;
      int rowb = m0 + wr*32 + r*16 + (lane >> 4)*4;
#pragma unroll
      for (int j = 0; j < 4; ++j) {
        int row = rowb + j;
        if (row >= M) continue;
        float v = acc[r][c][j];
        float* cp = C + (size_t)row*ldc + col;
        if (atomic) atomicAdd(cp, v);
        else        *cp = v;
      }
    }
  }
}

// ---------------------------------------------------------------------------
// xdbl GEMM with conv+SiLU fused into A-staging (MFMA + split-K + atomic).
// A[t][d] = silu(bc[d] + sum_j xz[t-3+j][d] * Wc[d][j]); C = A @ Wx^T.
// M=L_TOK, N=44, K=DI. grid = (1, 25, KSPLIT). C must be zero-initialized.
// ---------------------------------------------------------------------------
__global__ __launch_bounds__(256) void cgemm_kernel(
    const float* __restrict__ xz,
    const float* __restrict__ Wc, const float* __restrict__ bc,
    const float* __restrict__ B, float* __restrict__ C, int ksl) {
  __shared__ unsigned short As[64*40];
  __shared__ unsigned short Bs[64*40];
  __shared__ float wcs[96][4];
  __shared__ float bcs[96];
  const int M = L_TOK, N = XDBL_N;
  int tid = threadIdx.x;
  int m0 = blockIdx.y * 64, n0 = 0;
  int kbase = blockIdx.z * ksl;
  int wave = tid >> 6, lane = tid & 63;
  int wr = wave >> 1, wc = wave & 1;
  int srow = tid >> 2;
  int skq  = (tid & 3) * 8;
  f32x4 acc[2][2];
#pragma unroll
  for (int i = 0; i < 2; ++i)
#pragma unroll
    for (int j = 0; j < 2; ++j) acc[i][j] = (f32x4){0.f,0.f,0.f,0.f};

  if (tid < 96) {
    *(float4*)wcs[tid] = *(const float4*)(Wc + (size_t)(kbase + tid)*4);
    bcs[tid] = bc[kbase + tid];
  }

  int t = m0 + srow;
  int bn = n0 + srow;
  bool a_ok = (t < M), b_ok = (bn < N);
  const float* bp = B + (size_t)bn*DI + kbase + skq;
  const float4 z4 = {0.f,0.f,0.f,0.f};
  int l15 = lane & 15, lk = (lane >> 4) * 8;
  __syncthreads();   // wcs/bcs ready

  int nt = ksl >> 5;
  for (int i = 0; i < nt; ++i) {
    int cg = kbase + i*32 + skq;      // channel base for this thread
    int wi = i*32 + skq;              // index into wcs/bcs slice
    // conv taps: rows t-3..t, channels cg..cg+7
    float tap[4][8];
#pragma unroll
    for (int j = 0; j < 4; ++j) {
      int ts = t - 3 + j;
      float4 v0 = z4, v1 = z4;
      if (a_ok && ts >= 0) {
        v0 = *(const float4*)(xz + (size_t)ts*(2*DI) + cg);
        v1 = *(const float4*)(xz + (size_t)ts*(2*DI) + cg + 4);
      }
      tap[j][0]=v0.x; tap[j][1]=v0.y; tap[j][2]=v0.z; tap[j][3]=v0.w;
      tap[j][4]=v1.x; tap[j][5]=v1.y; tap[j][6]=v1.z; tap[j][7]=v1.w;
    }
    float4 bv0 = b_ok ? *(const float4*)(bp + i*32)     : z4;
    float4 bv1 = b_ok ? *(const float4*)(bp + i*32 + 4) : z4;
    short8 pa, pb;
#pragma unroll
    for (int c = 0; c < 8; ++c) {
      float u = bcs[wi + c];
#pragma unroll
      for (int j = 0; j < 4; ++j) u = fmaf(tap[j][c], wcs[wi + c][j], u);
      u = u / (1.0f + expf(-u));
      pa[c] = (short)f2bf(u);
    }
    pb[0]=f2bf(bv0.x); pb[1]=f2bf(bv0.y); pb[2]=f2bf(bv0.z); pb[3]=f2bf(bv0.w);
    pb[4]=f2bf(bv1.x); pb[5]=f2bf(bv1.y); pb[6]=f2bf(bv1.z); pb[7]=f2bf(bv1.w);
    *(short8*)&As[srow*40 + skq] = pa;
    *(short8*)&Bs[srow*40 + skq] = pb;
    __syncthreads();
    short8 af0 = *(const short8*)&As[(wr*32      + l15)*40 + lk];
    short8 af1 = *(const short8*)&As[(wr*32 + 16 + l15)*40 + lk];
    short8 bf0 = *(const short8*)&Bs[(wc*32      + l15)*40 + lk];
    short8 bf1 = *(const short8*)&Bs[(wc*32 + 16 + l15)*40 + lk];
    acc[0][0] = __builtin_amdgcn_mfma_f32_16x16x32_bf16(af0, bf0, acc[0][0], 0, 0, 0);
    acc[0][1] = __builtin_amdgcn_mfma_f32_16x16x32_bf16(af0, bf1, acc[0][1], 0, 0, 0);
    acc[1][0] = __builtin_amdgcn_mfma_f32_16x16x32_bf16(af1, bf0, acc[1][0], 0, 0, 0);
    acc[1][1] = __builtin_amdgcn_mfma_f32_16x16x32_bf16(af1, bf1, acc[1][1], 0, 0, 0);
    __syncthreads();
  }

#pragma unroll
  for (int r = 0; r < 2; ++r) {
#pragma unroll
    for (int c = 0; c < 2; ++c) {
      int col = n0 + wc*32 + c*16 + l15;
      if (col >= N) continue;
      int rowb = m0 + wr*32 + r*16 + (lane >> 4)*4;
#pragma unroll
      for (int j = 0; j < 4; ++j) {
        int row = rowb + j;
        if (row >= M) continue;
        atomicAdd(C + (size_t)row*XDBL_N + col, acc[r][c][j]);
      }
    }
  }
}

// ---------------------------------------------------------------------------
// Selective scan. conv+SiLU and delta = softplus(xdbl[:, :12] @ W_dt^T + b_dt)
// recomputed in-block from xz / xdbl.
// ---------------------------------------------------------------------------
__device__ __forceinline__ void scan_stage_common(
    const float* __restrict__ xz, const float* __restrict__ xdbl,
    const float* __restrict__ Wc, const float* __restrict__ bc,
    const float* __restrict__ W_dt, const float* __restrict__ b_dt,
    int d0, int t0,
    float xs[CLEN+3][16], float us[CLEN][16], float ds[CLEN][16],
    float bs[CLEN][16], float xd12[CLEN][12],
    float wdt[16][12], float wcs[16][4], float bds[16], float bcs[16],
    float cs[CLEN][16], float zs[CLEN][16], bool p3) {
  int tid = threadIdx.x;
  for (int i = tid; i < (CLEN+3)*16; i += 256) {
    int tt = i >> 4, dd = i & 15;
    int t = t0 + tt - 3;
    xs[tt][dd] = (t >= 0 && t < L_TOK) ? xz[(size_t)t*(2*DI) + d0 + dd] : 0.0f;
  }
  for (int i = tid; i < CLEN*XDBL_N; i += 256) {
    int tt = i / XDBL_N, c = i % XDBL_N;
    int t = t0 + tt;
    float v = (t < L_TOK) ? xdbl[(size_t)t*XDBL_N + c] : 0.0f;
    if (c < 12) xd12[tt][c] = v;
    else if (c < 28) bs[tt][c-12] = v;
    else if (p3) cs[tt][c-28] = v;
  }
  if (p3) {
    for (int i = tid; i < CLEN*16; i += 256) {
      int tt = i >> 4, dd = i & 15;
      int t = t0 + tt;
      zs[tt][dd] = (t < L_TOK) ? xz[(size_t)t*(2*DI) + DI + d0 + dd] : 0.0f;
    }
  }
  if (tid < 192) wdt[tid/12][tid%12] = W_dt[(d0 + tid/12)*DTR + tid%12];
  if (tid < 64)  wcs[tid>>2][tid&3]  = Wc[(d0 + (tid>>2))*DCONV + (tid&3)];
  if (tid < 16)  { bds[tid] = b_dt[d0+tid]; bcs[tid] = bc[d0+tid]; }
  __syncthreads();
  for (int i = tid; i < CLEN*16; i += 256) {
    int tt = i >> 4, dd = i & 15;
    float u = bcs[dd];
#pragma unroll
    for (int j = 0; j < 4; ++j) u = fmaf(xs[tt+j][dd], wcs[dd][j], u);
    us[tt][dd] = u / (1.0f + expf(-u));
    float v = bds[dd];
#pragma unroll
    for (int r = 0; r < 12; ++r) v = fmaf(xd12[tt][r], wdt[dd][r], v);
    ds[tt][dd] = (v > 20.0f) ? v : log1pf(expf(v));
  }
  __syncthreads();
}

__global__ __launch_bounds__(256) void scan_p1(
    const float* __restrict__ xz, const float* __restrict__ xdbl,
    const float* __restrict__ Wc, const float* __restrict__ bc,
    const float* __restrict__ W_dt, const float* __restrict__ b_dt,
    const float* __restrict__ A_log,
    float* __restrict__ cP, float* __restrict__ cS) {
  __shared__ float xs[CLEN+3][16], us[CLEN][16], ds[CLEN][16], bs[CLEN][16];
  __shared__ float xd12[CLEN][12], wdt[16][12], wcs[16][4], bds[16], bcs[16];
  int dl = threadIdx.x >> 4, n = threadIdx.x & 15;
  int d0 = blockIdx.x * 16;
  int t0 = blockIdx.y * CLEN;
  int nt = min(CLEN, L_TOK - t0);
  scan_stage_common(xz, xdbl, Wc, bc, W_dt, b_dt, d0, t0,
                    xs, us, ds, bs, xd12, wdt, wcs, bds, bcs,
                    us, us, false);
  int d = d0 + dl;
  float a2 = -expf(A_log[d*DS + n]) * 1.44269504088896340736f;
  float s = 0.0f, P = 1.0f;
  for (int tt = 0; tt < nt; ++tt) {
    float dlt = ds[tt][dl], uu = us[tt][dl], Bv = bs[tt][n];
    float dA = exp2f(dlt * a2);
    s = fmaf(dA, s, dlt * Bv * uu);
    P *= dA;
  }
  int o = (blockIdx.y * DI + d) * DS + n;
  cP[o] = P;
  cS[o] = s;
}

__global__ __launch_bounds__(256) void scan_p2(
    const float* __restrict__ cP, const float* __restrict__ cS,
    float* __restrict__ cIn) {
  int idx = blockIdx.x * 256 + threadIdx.x;
  float in = 0.0f;
  for (int c = 0; c < NCHUNK; ++c) {
    int o = c * (DI*DS) + idx;
    cIn[o] = in;
    in = fmaf(cP[o], in, cS[o]);
  }
}

__global__ __launch_bounds__(256) void scan_p3(
    const float* __restrict__ xz, const float* __restrict__ xdbl,
    const float* __restrict__ Wc, const float* __restrict__ bc,
    const float* __restrict__ W_dt, const float* __restrict__ b_dt,
    const float* __restrict__ A_log, const float* __restrict__ Dp,
    const float* __restrict__ cIn, float* __restrict__ yy) {
  __shared__ float xs[CLEN+3][16], us[CLEN][16], ds[CLEN][16], bs[CLEN][16];
  __shared__ float cs[CLEN][16], zs[CLEN][16];
  __shared__ float xd12[CLEN][12], wdt[16][12], wcs[16][4], bds[16], bcs[16];
  int dl = threadIdx.x >> 4, n = threadIdx.x & 15;
  int d0 = blockIdx.x * 16;
  int t0 = blockIdx.y * CLEN;
  int nt = min(CLEN, L_TOK - t0);
  scan_stage_common(xz, xdbl, Wc, bc, W_dt, b_dt, d0, t0,
                    xs, us, ds, bs, xd12, wdt, wcs, bds, bcs,
                    cs, zs, true);
  int d = d0 + dl;
  float a2 = -expf(A_log[d*DS + n]) * 1.44269504088896340736f;
  float s = cIn[(blockIdx.y * DI + d) * DS + n];
  float dpv = Dp[d];
  for (int tt = 0; tt < nt; ++tt) {
    float dlt = ds[tt][dl], uu = us[tt][dl], Bv = bs[tt][n];
    float dA = exp2f(dlt * a2);
    s = fmaf(dA, s, dlt * Bv * uu);
    float p = s * cs[tt][n];
    p += __shfl_xor(p, 1, 64);
    p += __shfl_xor(p, 2, 64);
    p += __shfl_xor(p, 4, 64);
    p += __shfl_xor(p, 8, 64);
    if (n == 0) {
      float z = zs[tt][dl];
      float y = fmaf(uu, dpv, p);
      y *= z / (1.0f + expf(-z));
      yy[(size_t)(t0 + tt)*DI + d] = y;
    }
  }
}

// ---------------------------------------------------------------------------
extern "C" void kernel_launch(void* const* d_in, const int* in_sizes, int n_in,
                              void* d_out, int out_size, void* d_ws, size_t ws_size,
                              hipStream_t stream) {
  const float* x       = (const float*)d_in[0];
  const float* patch_w = (const float*)d_in[1];
  const float* patch_b = (const float*)d_in[2];
  const float* cls_tok = (const float*)d_in[3];
  const float* pos_emb = (const float*)d_in[4];
  const float* ln_g    = (const float*)d_in[5];
  const float* ln_b    = (const float*)d_in[6];
  const float* W_in    = (const float*)d_in[7];
  const float* Wc      = (const float*)d_in[8];
  const float* bc      = (const float*)d_in[9];
  const float* Wx      = (const float*)d_in[10];
  const float* W_dt    = (const float*)d_in[11];
  const float* b_dt    = (const float*)d_in[12];
  const float* A_log   = (const float*)d_in[13];
  const float* Dp      = (const float*)d_in[14];
  const float* W_out   = (const float*)d_in[15];
  const float* fn_g    = (const float*)d_in[16];
  const float* fn_b    = (const float*)d_in[17];

  float* ws = (float*)d_ws;
  float* cur   = ws;                       // 1569*192
  float* h     = cur   + L_TOK*DM;         // 1569*192
  float* xz    = h     + L_TOK*DM;         // 1569*768 (aliases px)
  float* xdbl  = xz    + L_TOK*2*DI;       // 1569*44
  float* yy    = xdbl  + L_TOK*XDBL_N;     // 1569*384
  float* cP    = yy    + L_TOK*DI;         // 25*6144
  float* cS    = cP    + NCHUNK*DI*DS;
  float* cIn   = cS    + NCHUNK*DI*DS;
  float* px    = xz;                       // im2col buffer, dead before layer 0's xz

  // im2col + cur init (pos + bias/cls)
  im2col_kernel<<<(NPATCH*192 + 255)/256, 256, 0, stream>>>(
      x, cls_tok, patch_b, pos_emb, px, cur);
  // patch GEMM: cur[1..] += px @ patch_w^T, M=1568, N=192, K=768, split-K 4
  {
    dim3 grid(DM/64, (NPATCH + 63)/64, 4);
    mgemm_kernel<<<grid, 256, 0, stream>>>(px, 768, patch_w, 768, cur + DM, DM,
                                           NPATCH, DM, 768/4, 1);
  }

  for (int dep = 0; dep < DEPTH; ++dep) {
    const float* g     = ln_g  + dep*DM;
    const float* bb    = ln_b  + dep*DM;
    const float* Win_l = W_in  + (size_t)dep*2*DI*DM;
    const float* Wc_l  = Wc    + (size_t)dep*DI*DCONV;
    const float* bc_l  = bc    + (size_t)dep*DI;
    const float* Wx_l  = Wx    + (size_t)dep*XDBL_N*DI;
    const float* Wdt_l = W_dt  + (size_t)dep*DI*DTR;
    const float* bdt_l = b_dt  + (size_t)dep*DI;
    const float* Alog_l= A_log + (size_t)dep*DI*DS;
    const float* Dp_l  = Dp    + (size_t)dep*DI;
    const float* Wout_l= W_out + (size_t)dep*DM*DI;

    // h = LN(cur); also zero xdbl for this layer's atomic split-K GEMM
    ln_kernel<<<L_TOK, 64, 0, stream>>>(cur, h, g, bb, xdbl);

    // xz = h @ W_in^T : M=1569, N=768, K=192 (no split, 300 blocks)
    {
      dim3 grid((2*DI)/64, (L_TOK + 63)/64, 1);
      mgemm_kernel<<<grid, 256, 0, stream>>>(h, DM, Win_l, DM, xz, 2*DI,
                                             L_TOK, 2*DI, DM, 0);
    }

    // xdbl = silu(conv(u)) @ Wx^T : M=1569, N=44, K=384, split-K 4, conv fused
    {
      dim3 grid(1, (L_TOK + 63)/64, 4);
      cgemm_kernel<<<grid, 256, 0, stream>>>(xz, Wc_l, bc_l, Wx_l, xdbl, DI/4);
    }

    // selective scan (3-phase chunked; conv+delta recomputed in-block)
    {
      dim3 g1(DI/16, NCHUNK);
      scan_p1<<<g1, 256, 0, stream>>>(xz, xdbl, Wc_l, bc_l, Wdt_l, bdt_l, Alog_l, cP, cS);
      scan_p2<<<(DI*DS)/256, 256, 0, stream>>>(cP, cS, cIn);
      scan_p3<<<g1, 256, 0, stream>>>(xz, xdbl, Wc_l, bc_l, Wdt_l, bdt_l, Alog_l,
                                      Dp_l, cIn, yy);
    }

    // cur += yy @ W_out^T : M=1569, N=192, K=384, split-K 4 (residual via atomic)
    {
      dim3 grid(DM/64, (L_TOK + 63)/64, 4);
      mgemm_kernel<<<grid, 256, 0, stream>>>(yy, DI, Wout_l, DI, cur, DM,
                                             L_TOK, DM, DI/4, 1);
    }
  }

  // final LN -> d_out
  ln_kernel<<<L_TOK, 64, 0, stream>>>(cur, (float*)d_out, fn_g, fn_b, nullptr);
}

// Round 6
// 701.092 us; speedup vs baseline: 1.8851x; 1.2661x over previous
//
#include <hip/hip_runtime.h>
#include <hip/hip_bf16.h>
#include <math.h>

#define L_TOK 1569
#define DM 192
#define DI 384
#define DS 16
#define DTR 12
#define DCONV 4
#define XDBL_N (DTR + 2*DS)   // 44
#define DEPTH 8
#define NCHUNK 25
#define CLEN 64
#define NPATCH 1568

typedef __attribute__((ext_vector_type(8))) short short8;
typedef __attribute__((ext_vector_type(4))) float f32x4;

__device__ __forceinline__ unsigned short f2bf(float f) {
  unsigned int u = __float_as_uint(f);
  u += 0x7FFFu + ((u >> 16) & 1u);   // round-to-nearest-even
  return (unsigned short)(u >> 16);
}

// ---------------------------------------------------------------------------
// im2col + cur init: px[patch][k] = x[c][t][h*16+p][w*16+q], k = c*256+p*16+q.
// Also initializes cur[tok][e] = pos[tok][e] + (tok==0 ? cls[e] : patch_b[e]).
// ---------------------------------------------------------------------------
__global__ __launch_bounds__(256) void im2col_kernel(
    const float* __restrict__ x, const float* __restrict__ cls,
    const float* __restrict__ pb, const float* __restrict__ pos,
    float* __restrict__ px, float* __restrict__ curp) {
  int gid = blockIdx.x * 256 + threadIdx.x;
  const int initN = (L_TOK * DM) / 4;   // 75312 float4s
  if (gid < initN) {
    int e4 = gid * 4;
    int tok = e4 / DM;
    int col = e4 % DM;
    float4 pv = *(const float4*)(pos + e4);
    float4 av = (tok == 0) ? *(const float4*)(cls + col)
                           : *(const float4*)(pb + col);
    float4 o = {pv.x + av.x, pv.y + av.y, pv.z + av.z, pv.w + av.w};
    *(float4*)(curp + e4) = o;
  }
  if (gid >= NPATCH * 192) return;      // 192 float4 per patch
  int patch = gid / 192;
  int r = gid % 192;
  int c = r / 64;
  int p = (r >> 2) & 15;
  int q = (r & 3) * 4;
  int t = patch / 196, hw = patch % 196, hh = hw / 14, w = hw % 14;
  const float* src = x + ((size_t)(c*8 + t)*224 + hh*16 + p)*224 + w*16 + q;
  *(float4*)(px + (size_t)patch*768 + r*4) = *(const float4*)src;
}

// ---------------------------------------------------------------------------
// Final LayerNorm over 192 features. One wave per token, 3 elems/lane.
// ---------------------------------------------------------------------------
__global__ __launch_bounds__(64) void ln_kernel(
    const float* __restrict__ in, float* __restrict__ out,
    const float* __restrict__ g, const float* __restrict__ b) {
  int tokn = blockIdx.x;
  int lane = threadIdx.x;
  const float* row = in + (size_t)tokn*DM;
  float x0 = row[lane], x1 = row[lane+64], x2 = row[lane+128];
  float s = x0 + x1 + x2;
  float s2 = x0*x0 + x1*x1 + x2*x2;
#pragma unroll
  for (int off = 1; off < 64; off <<= 1) {
    s  += __shfl_xor(s,  off, 64);
    s2 += __shfl_xor(s2, off, 64);
  }
  float m = s * (1.0f/192.0f);
  float v = s2 * (1.0f/192.0f) - m*m;
  float rs = rsqrtf(v + 1e-5f);
  float* orow = out + (size_t)tokn*DM;
  orow[lane]     = (x0 - m)*rs*g[lane]     + b[lane];
  orow[lane+64]  = (x1 - m)*rs*g[lane+64]  + b[lane+64];
  orow[lane+128] = (x2 - m)*rs*g[lane+128] + b[lane+128];
}

// ---------------------------------------------------------------------------
// Fused LN + xz GEMM: xz[M=1569, N=768] = LN(cur) @ W_in^T, K=192 all in LDS.
// Each block: 64 tokens x 64 cols; LN computed in-register (4 thr/row);
// one barrier before 6 unrolled MFMA k-steps. blockIdx.x==0 blocks also
// zero this tile's xdbl rows (for the atomic split-K cgemm downstream).
// ---------------------------------------------------------------------------
__global__ __launch_bounds__(256) void lnxz_kernel(
    const float* __restrict__ cur, const float* __restrict__ g,
    const float* __restrict__ b, const float* __restrict__ W,
    float* __restrict__ xz, float* __restrict__ xdbl_z) {
  __shared__ unsigned short As[64][200];
  __shared__ unsigned short Bs[64][200];
  __shared__ float gs[192], bs2[192];
  int tid = threadIdx.x;
  int m0 = blockIdx.y * 64, n0 = blockIdx.x * 64;
  int wave = tid >> 6, lane = tid & 63;
  int wr = wave >> 1, wc = wave & 1;
  int l15 = lane & 15, lk = (lane >> 4) * 8;

  for (int i = tid; i < 192; i += 256) { gs[i] = g[i]; bs2[i] = b[i]; }

  if (blockIdx.x == 0) {
    for (int i = tid; i < 64*11; i += 256) {
      int r = i / 11, q = i % 11;
      int row = m0 + r;
      if (row < L_TOK) {
        float4 z = {0.f,0.f,0.f,0.f};
        *(float4*)(xdbl_z + (size_t)row*XDBL_N + q*4) = z;
      }
    }
  }

  int r = tid >> 2, c0 = (tid & 3) * 48;
  // --- LN of row m0+r (4 threads per row, 48 cols each) ---
  float v[48];
  {
    int row = m0 + r;
    if (row < L_TOK) {
      const float* rp = cur + (size_t)row*DM + c0;
#pragma unroll
      for (int j = 0; j < 12; ++j) {
        float4 t4 = *(const float4*)(rp + j*4);
        v[j*4+0]=t4.x; v[j*4+1]=t4.y; v[j*4+2]=t4.z; v[j*4+3]=t4.w;
      }
    } else {
#pragma unroll
      for (int j = 0; j < 48; ++j) v[j] = 0.f;
    }
  }
  float s = 0.f, s2 = 0.f;
#pragma unroll
  for (int j = 0; j < 48; ++j) { s += v[j]; s2 += v[j]*v[j]; }
  s  += __shfl_xor(s, 1, 64); s2 += __shfl_xor(s2, 1, 64);
  s  += __shfl_xor(s, 2, 64); s2 += __shfl_xor(s2, 2, 64);
  float mu = s * (1.0f/192.0f);
  float var = s2 * (1.0f/192.0f) - mu*mu;
  float rsd = rsqrtf(var + 1e-5f);

  __syncthreads();   // gs/bs2 ready
#pragma unroll
  for (int j = 0; j < 48; ++j) {
    int k = c0 + j;
    As[r][k] = f2bf((v[j] - mu)*rsd*gs[k] + bs2[k]);
  }
  // --- stage B (W rows n0..n0+63, K=192) ---
  {
    const float* rp = W + (size_t)(n0 + r)*DM + c0;
#pragma unroll
    for (int j = 0; j < 12; ++j) {
      float4 t4 = *(const float4*)(rp + j*4);
      Bs[r][c0+j*4+0]=f2bf(t4.x); Bs[r][c0+j*4+1]=f2bf(t4.y);
      Bs[r][c0+j*4+2]=f2bf(t4.z); Bs[r][c0+j*4+3]=f2bf(t4.w);
    }
  }
  __syncthreads();

  f32x4 acc[2][2];
#pragma unroll
  for (int i = 0; i < 2; ++i)
#pragma unroll
    for (int j = 0; j < 2; ++j) acc[i][j] = (f32x4){0.f,0.f,0.f,0.f};

#pragma unroll
  for (int kk = 0; kk < 6; ++kk) {
    short8 af0 = *(const short8*)&As[wr*32      + l15][kk*32 + lk];
    short8 af1 = *(const short8*)&As[wr*32 + 16 + l15][kk*32 + lk];
    short8 bf0 = *(const short8*)&Bs[wc*32      + l15][kk*32 + lk];
    short8 bf1 = *(const short8*)&Bs[wc*32 + 16 + l15][kk*32 + lk];
    acc[0][0] = __builtin_amdgcn_mfma_f32_16x16x32_bf16(af0, bf0, acc[0][0], 0, 0, 0);
    acc[0][1] = __builtin_amdgcn_mfma_f32_16x16x32_bf16(af0, bf1, acc[0][1], 0, 0, 0);
    acc[1][0] = __builtin_amdgcn_mfma_f32_16x16x32_bf16(af1, bf0, acc[1][0], 0, 0, 0);
    acc[1][1] = __builtin_amdgcn_mfma_f32_16x16x32_bf16(af1, bf1, acc[1][1], 0, 0, 0);
  }

#pragma unroll
  for (int rr = 0; rr < 2; ++rr) {
#pragma unroll
    for (int cc = 0; cc < 2; ++cc) {
      int col = n0 + wc*32 + cc*16 + l15;
      int rowb = m0 + wr*32 + rr*16 + (lane >> 4)*4;
#pragma unroll
      for (int j = 0; j < 4; ++j) {
        int row = rowb + j;
        if (row < L_TOK) xz[(size_t)row*(2*DI) + col] = acc[rr][cc][j];
      }
    }
  }
}

// ---------------------------------------------------------------------------
// MFMA bf16 GEMM with split-K: C[M,N] (+)= A[M,K_slice] * B[N,K_slice]^T.
// atomic=0: plain store (KSPLIT must be 1). atomic=1: atomicAdd (C pre-init).
// ---------------------------------------------------------------------------
__global__ __launch_bounds__(256) void mgemm_kernel(
    const float* __restrict__ A, int lda,
    const float* __restrict__ B, int ldb,
    float* __restrict__ C, int ldc,
    int M, int N, int ksl, int atomic) {
  __shared__ unsigned short As[64*40];
  __shared__ unsigned short Bs[64*40];
  int tid = threadIdx.x;
  int m0 = blockIdx.y * 64, n0 = blockIdx.x * 64;
  int kbase = blockIdx.z * ksl;
  int wave = tid >> 6, lane = tid & 63;
  int wr = wave >> 1, wc = wave & 1;
  int srow = tid >> 2;          // 0..63
  int skq  = (tid & 3) * 8;     // 0,8,16,24
  f32x4 acc[2][2];
#pragma unroll
  for (int i = 0; i < 2; ++i)
#pragma unroll
    for (int j = 0; j < 2; ++j) acc[i][j] = (f32x4){0.f,0.f,0.f,0.f};

  int am = m0 + srow;
  int bn = n0 + srow;
  bool a_ok = (am < M), b_ok = (bn < N);
  const float* ap = A + (size_t)am*lda + kbase + skq;
  const float* bp = B + (size_t)bn*ldb + kbase + skq;
  const float4 z4 = {0.f,0.f,0.f,0.f};
  int l15 = lane & 15, lk = (lane >> 4) * 8;

  int nt = ksl >> 5;
  float4 a0 = a_ok ? *(const float4*)(ap)     : z4;
  float4 a1 = a_ok ? *(const float4*)(ap + 4) : z4;
  float4 b0 = b_ok ? *(const float4*)(bp)     : z4;
  float4 b1 = b_ok ? *(const float4*)(bp + 4) : z4;

  for (int i = 0; i < nt; ++i) {
    {
      short8 pa, pb;
      pa[0]=f2bf(a0.x); pa[1]=f2bf(a0.y); pa[2]=f2bf(a0.z); pa[3]=f2bf(a0.w);
      pa[4]=f2bf(a1.x); pa[5]=f2bf(a1.y); pa[6]=f2bf(a1.z); pa[7]=f2bf(a1.w);
      pb[0]=f2bf(b0.x); pb[1]=f2bf(b0.y); pb[2]=f2bf(b0.z); pb[3]=f2bf(b0.w);
      pb[4]=f2bf(b1.x); pb[5]=f2bf(b1.y); pb[6]=f2bf(b1.z); pb[7]=f2bf(b1.w);
      *(short8*)&As[srow*40 + skq] = pa;
      *(short8*)&Bs[srow*40 + skq] = pb;
    }
    __syncthreads();
    bool pf = (i + 1 < nt);
    int k0n = (i + 1) << 5;
    a0 = (pf && a_ok) ? *(const float4*)(ap + k0n)     : z4;
    a1 = (pf && a_ok) ? *(const float4*)(ap + k0n + 4) : z4;
    b0 = (pf && b_ok) ? *(const float4*)(bp + k0n)     : z4;
    b1 = (pf && b_ok) ? *(const float4*)(bp + k0n + 4) : z4;

    short8 af0 = *(const short8*)&As[(wr*32      + l15)*40 + lk];
    short8 af1 = *(const short8*)&As[(wr*32 + 16 + l15)*40 + lk];
    short8 bf0 = *(const short8*)&Bs[(wc*32      + l15)*40 + lk];
    short8 bf1 = *(const short8*)&Bs[(wc*32 + 16 + l15)*40 + lk];
    acc[0][0] = __builtin_amdgcn_mfma_f32_16x16x32_bf16(af0, bf0, acc[0][0], 0, 0, 0);
    acc[0][1] = __builtin_amdgcn_mfma_f32_16x16x32_bf16(af0, bf1, acc[0][1], 0, 0, 0);
    acc[1][0] = __builtin_amdgcn_mfma_f32_16x16x32_bf16(af1, bf0, acc[1][0], 0, 0, 0);
    acc[1][1] = __builtin_amdgcn_mfma_f32_16x16x32_bf16(af1, bf1, acc[1][1], 0, 0, 0);
    __syncthreads();
  }

#pragma unroll
  for (int r = 0; r < 2; ++r) {
#pragma unroll
    for (int c = 0; c < 2; ++c) {
      int col = n0 + wc*32 + c*16 + l15;
      if (col >= N) continue;
      int rowb = m0 + wr*32 + r*16 + (lane >> 4)*4;
#pragma unroll
      for (int j = 0; j < 4; ++j) {
        int row = rowb + j;
        if (row >= M) continue;
        float v = acc[r][c][j];
        float* cp = C + (size_t)row*ldc + col;
        if (atomic) atomicAdd(cp, v);
        else        *cp = v;
      }
    }
  }
}

// ---------------------------------------------------------------------------
// xdbl GEMM with conv+SiLU fused into A-staging (MFMA + split-K + atomic).
// A[t][d] = silu(bc[d] + sum_j xz[t-3+j][d] * Wc[d][j]); C = A @ Wx^T.
// M=L_TOK, N=44, K=DI. grid = (1, 25, KSPLIT). C must be zero-initialized.
// ---------------------------------------------------------------------------
__global__ __launch_bounds__(256) void cgemm_kernel(
    const float* __restrict__ xz,
    const float* __restrict__ Wc, const float* __restrict__ bc,
    const float* __restrict__ B, float* __restrict__ C, int ksl) {
  __shared__ unsigned short As[64*40];
  __shared__ unsigned short Bs[64*40];
  __shared__ float wcs[96][4];
  __shared__ float bcs[96];
  const int M = L_TOK, N = XDBL_N;
  int tid = threadIdx.x;
  int m0 = blockIdx.y * 64, n0 = 0;
  int kbase = blockIdx.z * ksl;
  int wave = tid >> 6, lane = tid & 63;
  int wr = wave >> 1, wc = wave & 1;
  int srow = tid >> 2;
  int skq  = (tid & 3) * 8;
  f32x4 acc[2][2];
#pragma unroll
  for (int i = 0; i < 2; ++i)
#pragma unroll
    for (int j = 0; j < 2; ++j) acc[i][j] = (f32x4){0.f,0.f,0.f,0.f};

  if (tid < 96) {
    *(float4*)wcs[tid] = *(const float4*)(Wc + (size_t)(kbase + tid)*4);
    bcs[tid] = bc[kbase + tid];
  }

  int t = m0 + srow;
  int bn = n0 + srow;
  bool a_ok = (t < M), b_ok = (bn < N);
  const float* bp = B + (size_t)bn*DI + kbase + skq;
  const float4 z4 = {0.f,0.f,0.f,0.f};
  int l15 = lane & 15, lk = (lane >> 4) * 8;
  __syncthreads();   // wcs/bcs ready

  int nt = ksl >> 5;
  for (int i = 0; i < nt; ++i) {
    int cg = kbase + i*32 + skq;
    int wi = i*32 + skq;
    float tap[4][8];
#pragma unroll
    for (int j = 0; j < 4; ++j) {
      int ts = t - 3 + j;
      float4 v0 = z4, v1 = z4;
      if (a_ok && ts >= 0) {
        v0 = *(const float4*)(xz + (size_t)ts*(2*DI) + cg);
        v1 = *(const float4*)(xz + (size_t)ts*(2*DI) + cg + 4);
      }
      tap[j][0]=v0.x; tap[j][1]=v0.y; tap[j][2]=v0.z; tap[j][3]=v0.w;
      tap[j][4]=v1.x; tap[j][5]=v1.y; tap[j][6]=v1.z; tap[j][7]=v1.w;
    }
    float4 bv0 = b_ok ? *(const float4*)(bp + i*32)     : z4;
    float4 bv1 = b_ok ? *(const float4*)(bp + i*32 + 4) : z4;
    short8 pa, pb;
#pragma unroll
    for (int c = 0; c < 8; ++c) {
      float u = bcs[wi + c];
#pragma unroll
      for (int j = 0; j < 4; ++j) u = fmaf(tap[j][c], wcs[wi + c][j], u);
      u = u / (1.0f + expf(-u));
      pa[c] = (short)f2bf(u);
    }
    pb[0]=f2bf(bv0.x); pb[1]=f2bf(bv0.y); pb[2]=f2bf(bv0.z); pb[3]=f2bf(bv0.w);
    pb[4]=f2bf(bv1.x); pb[5]=f2bf(bv1.y); pb[6]=f2bf(bv1.z); pb[7]=f2bf(bv1.w);
    *(short8*)&As[srow*40 + skq] = pa;
    *(short8*)&Bs[srow*40 + skq] = pb;
    __syncthreads();
    short8 af0 = *(const short8*)&As[(wr*32      + l15)*40 + lk];
    short8 af1 = *(const short8*)&As[(wr*32 + 16 + l15)*40 + lk];
    short8 bf0 = *(const short8*)&Bs[(wc*32      + l15)*40 + lk];
    short8 bf1 = *(const short8*)&Bs[(wc*32 + 16 + l15)*40 + lk];
    acc[0][0] = __builtin_amdgcn_mfma_f32_16x16x32_bf16(af0, bf0, acc[0][0], 0, 0, 0);
    acc[0][1] = __builtin_amdgcn_mfma_f32_16x16x32_bf16(af0, bf1, acc[0][1], 0, 0, 0);
    acc[1][0] = __builtin_amdgcn_mfma_f32_16x16x32_bf16(af1, bf0, acc[1][0], 0, 0, 0);
    acc[1][1] = __builtin_amdgcn_mfma_f32_16x16x32_bf16(af1, bf1, acc[1][1], 0, 0, 0);
    __syncthreads();
  }

#pragma unroll
  for (int r = 0; r < 2; ++r) {
#pragma unroll
    for (int c = 0; c < 2; ++c) {
      int col = n0 + wc*32 + c*16 + l15;
      if (col >= N) continue;
      int rowb = m0 + wr*32 + r*16 + (lane >> 4)*4;
#pragma unroll
      for (int j = 0; j < 4; ++j) {
        int row = rowb + j;
        if (row >= M) continue;
        atomicAdd(C + (size_t)row*XDBL_N + col, acc[r][c][j]);
      }
    }
  }
}

// ---------------------------------------------------------------------------
// Selective scan. conv+SiLU and delta = softplus(xdbl[:, :12] @ W_dt^T + b_dt)
// recomputed in-block from xz / xdbl.
// ---------------------------------------------------------------------------
__device__ __forceinline__ void scan_stage_common(
    const float* __restrict__ xz, const float* __restrict__ xdbl,
    const float* __restrict__ Wc, const float* __restrict__ bc,
    const float* __restrict__ W_dt, const float* __restrict__ b_dt,
    int d0, int t0,
    float xs[CLEN+3][16], float us[CLEN][16], float ds[CLEN][16],
    float bs[CLEN][16], float xd12[CLEN][12],
    float wdt[16][12], float wcs[16][4], float bds[16], float bcs[16],
    float cs[CLEN][16], float zs[CLEN][16], bool p3) {
  int tid = threadIdx.x;
  for (int i = tid; i < (CLEN+3)*16; i += 256) {
    int tt = i >> 4, dd = i & 15;
    int t = t0 + tt - 3;
    xs[tt][dd] = (t >= 0 && t < L_TOK) ? xz[(size_t)t*(2*DI) + d0 + dd] : 0.0f;
  }
  for (int i = tid; i < CLEN*XDBL_N; i += 256) {
    int tt = i / XDBL_N, c = i % XDBL_N;
    int t = t0 + tt;
    float v = (t < L_TOK) ? xdbl[(size_t)t*XDBL_N + c] : 0.0f;
    if (c < 12) xd12[tt][c] = v;
    else if (c < 28) bs[tt][c-12] = v;
    else if (p3) cs[tt][c-28] = v;
  }
  if (p3) {
    for (int i = tid; i < CLEN*16; i += 256) {
      int tt = i >> 4, dd = i & 15;
      int t = t0 + tt;
      zs[tt][dd] = (t < L_TOK) ? xz[(size_t)t*(2*DI) + DI + d0 + dd] : 0.0f;
    }
  }
  if (tid < 192) wdt[tid/12][tid%12] = W_dt[(d0 + tid/12)*DTR + tid%12];
  if (tid < 64)  wcs[tid>>2][tid&3]  = Wc[(d0 + (tid>>2))*DCONV + (tid&3)];
  if (tid < 16)  { bds[tid] = b_dt[d0+tid]; bcs[tid] = bc[d0+tid]; }
  __syncthreads();
  for (int i = tid; i < CLEN*16; i += 256) {
    int tt = i >> 4, dd = i & 15;
    float u = bcs[dd];
#pragma unroll
    for (int j = 0; j < 4; ++j) u = fmaf(xs[tt+j][dd], wcs[dd][j], u);
    us[tt][dd] = u / (1.0f + expf(-u));
    float v = bds[dd];
#pragma unroll
    for (int r = 0; r < 12; ++r) v = fmaf(xd12[tt][r], wdt[dd][r], v);
    ds[tt][dd] = (v > 20.0f) ? v : log1pf(expf(v));
  }
  __syncthreads();
}

__global__ __launch_bounds__(256) void scan_p1(
    const float* __restrict__ xz, const float* __restrict__ xdbl,
    const float* __restrict__ Wc, const float* __restrict__ bc,
    const float* __restrict__ W_dt, const float* __restrict__ b_dt,
    const float* __restrict__ A_log,
    float* __restrict__ cP, float* __restrict__ cS) {
  __shared__ float xs[CLEN+3][16], us[CLEN][16], ds[CLEN][16], bs[CLEN][16];
  __shared__ float xd12[CLEN][12], wdt[16][12], wcs[16][4], bds[16], bcs[16];
  int dl = threadIdx.x >> 4, n = threadIdx.x & 15;
  int d0 = blockIdx.x * 16;
  int t0 = blockIdx.y * CLEN;
  int nt = min(CLEN, L_TOK - t0);
  scan_stage_common(xz, xdbl, Wc, bc, W_dt, b_dt, d0, t0,
                    xs, us, ds, bs, xd12, wdt, wcs, bds, bcs,
                    us, us, false);
  int d = d0 + dl;
  float a2 = -expf(A_log[d*DS + n]) * 1.44269504088896340736f;
  float s = 0.0f, P = 1.0f;
  for (int tt = 0; tt < nt; ++tt) {
    float dlt = ds[tt][dl], uu = us[tt][dl], Bv = bs[tt][n];
    float dA = exp2f(dlt * a2);
    s = fmaf(dA, s, dlt * Bv * uu);
    P *= dA;
  }
  int o = (blockIdx.y * DI + d) * DS + n;
  cP[o] = P;
  cS[o] = s;
}

// Phase 3 with merged chunk-carry: each block computes its own carry-in by
// scanning cP/cS over preceding chunks (coalesced; thread = its (d,n) slot).
__global__ __launch_bounds__(256) void scan_p3(
    const float* __restrict__ xz, const float* __restrict__ xdbl,
    const float* __restrict__ Wc, const float* __restrict__ bc,
    const float* __restrict__ W_dt, const float* __restrict__ b_dt,
    const float* __restrict__ A_log, const float* __restrict__ Dp,
    const float* __restrict__ cP, const float* __restrict__ cS,
    float* __restrict__ yy) {
  __shared__ float xs[CLEN+3][16], us[CLEN][16], ds[CLEN][16], bs[CLEN][16];
  __shared__ float cs[CLEN][16], zs[CLEN][16];
  __shared__ float xd12[CLEN][12], wdt[16][12], wcs[16][4], bds[16], bcs[16];
  int dl = threadIdx.x >> 4, n = threadIdx.x & 15;
  int d0 = blockIdx.x * 16;
  int t0 = blockIdx.y * CLEN;
  int nt = min(CLEN, L_TOK - t0);
  int d = d0 + dl;
  // carry-in scan over preceding chunks (before staging barrier: independent)
  float s = 0.0f;
  {
    int ncar = blockIdx.y;
    int o = d * DS + n;
#pragma unroll 4
    for (int c = 0; c < ncar; ++c) {
      s = fmaf(cP[(size_t)c*(DI*DS) + o], s, cS[(size_t)c*(DI*DS) + o]);
    }
  }
  scan_stage_common(xz, xdbl, Wc, bc, W_dt, b_dt, d0, t0,
                    xs, us, ds, bs, xd12, wdt, wcs, bds, bcs,
                    cs, zs, true);
  float a2 = -expf(A_log[d*DS + n]) * 1.44269504088896340736f;
  float dpv = Dp[d];
  for (int tt = 0; tt < nt; ++tt) {
    float dlt = ds[tt][dl], uu = us[tt][dl], Bv = bs[tt][n];
    float dA = exp2f(dlt * a2);
    s = fmaf(dA, s, dlt * Bv * uu);
    float p = s * cs[tt][n];
    p += __shfl_xor(p, 1, 64);
    p += __shfl_xor(p, 2, 64);
    p += __shfl_xor(p, 4, 64);
    p += __shfl_xor(p, 8, 64);
    if (n == 0) {
      float z = zs[tt][dl];
      float y = fmaf(uu, dpv, p);
      y *= z / (1.0f + expf(-z));
      yy[(size_t)(t0 + tt)*DI + d] = y;
    }
  }
}

// ---------------------------------------------------------------------------
extern "C" void kernel_launch(void* const* d_in, const int* in_sizes, int n_in,
                              void* d_out, int out_size, void* d_ws, size_t ws_size,
                              hipStream_t stream) {
  const float* x       = (const float*)d_in[0];
  const float* patch_w = (const float*)d_in[1];
  const float* patch_b = (const float*)d_in[2];
  const float* cls_tok = (const float*)d_in[3];
  const float* pos_emb = (const float*)d_in[4];
  const float* ln_g    = (const float*)d_in[5];
  const float* ln_b    = (const float*)d_in[6];
  const float* W_in    = (const float*)d_in[7];
  const float* Wc      = (const float*)d_in[8];
  const float* bc      = (const float*)d_in[9];
  const float* Wx      = (const float*)d_in[10];
  const float* W_dt    = (const float*)d_in[11];
  const float* b_dt    = (const float*)d_in[12];
  const float* A_log   = (const float*)d_in[13];
  const float* Dp      = (const float*)d_in[14];
  const float* W_out   = (const float*)d_in[15];
  const float* fn_g    = (const float*)d_in[16];
  const float* fn_b    = (const float*)d_in[17];

  float* ws = (float*)d_ws;
  float* cur   = ws;                       // 1569*192
  float* xz    = cur   + L_TOK*DM;         // 1569*768 (aliases px)
  float* xdbl  = xz    + L_TOK*2*DI;       // 1569*44
  float* yy    = xdbl  + L_TOK*XDBL_N;     // 1569*384
  float* cP    = yy    + L_TOK*DI;         // 25*6144
  float* cS    = cP    + NCHUNK*DI*DS;
  float* px    = xz;                       // im2col buffer, dead before layer 0's xz

  // im2col + cur init (pos + bias/cls)
  im2col_kernel<<<(NPATCH*192 + 255)/256, 256, 0, stream>>>(
      x, cls_tok, patch_b, pos_emb, px, cur);
  // patch GEMM: cur[1..] += px @ patch_w^T, M=1568, N=192, K=768, split-K 4
  {
    dim3 grid(DM/64, (NPATCH + 63)/64, 4);
    mgemm_kernel<<<grid, 256, 0, stream>>>(px, 768, patch_w, 768, cur + DM, DM,
                                           NPATCH, DM, 768/4, 1);
  }

  for (int dep = 0; dep < DEPTH; ++dep) {
    const float* g     = ln_g  + dep*DM;
    const float* bb    = ln_b  + dep*DM;
    const float* Win_l = W_in  + (size_t)dep*2*DI*DM;
    const float* Wc_l  = Wc    + (size_t)dep*DI*DCONV;
    const float* bc_l  = bc    + (size_t)dep*DI;
    const float* Wx_l  = Wx    + (size_t)dep*XDBL_N*DI;
    const float* Wdt_l = W_dt  + (size_t)dep*DI*DTR;
    const float* bdt_l = b_dt  + (size_t)dep*DI;
    const float* Alog_l= A_log + (size_t)dep*DI*DS;
    const float* Dp_l  = Dp    + (size_t)dep*DI;
    const float* Wout_l= W_out + (size_t)dep*DM*DI;

    // xz = LN(cur) @ W_in^T (fused; also zeroes xdbl)
    {
      dim3 grid((2*DI)/64, (L_TOK + 63)/64);
      lnxz_kernel<<<grid, 256, 0, stream>>>(cur, g, bb, Win_l, xz, xdbl);
    }

    // xdbl = silu(conv(u)) @ Wx^T : M=1569, N=44, K=384, split-K 4, conv fused
    {
      dim3 grid(1, (L_TOK + 63)/64, 4);
      cgemm_kernel<<<grid, 256, 0, stream>>>(xz, Wc_l, bc_l, Wx_l, xdbl, DI/4);
    }

    // selective scan (p1 + p3-with-merged-carry)
    {
      dim3 g1(DI/16, NCHUNK);
      scan_p1<<<g1, 256, 0, stream>>>(xz, xdbl, Wc_l, bc_l, Wdt_l, bdt_l, Alog_l, cP, cS);
      scan_p3<<<g1, 256, 0, stream>>>(xz, xdbl, Wc_l, bc_l, Wdt_l, bdt_l, Alog_l,
                                      Dp_l, cP, cS, yy);
    }

    // cur += yy @ W_out^T : M=1569, N=192, K=384, split-K 4 (residual via atomic)
    {
      dim3 grid(DM/64, (L_TOK + 63)/64, 4);
      mgemm_kernel<<<grid, 256, 0, stream>>>(yy, DI, Wout_l, DI, cur, DM,
                                             L_TOK, DM, DI/4, 1);
    }
  }

  // final LN -> d_out
  ln_kernel<<<L_TOK, 64, 0, stream>>>(cur, (float*)d_out, fn_g, fn_b);
}